// Round 4
// baseline (181.409 us; speedup 1.0000x reference)
//
#include <hip/hip_runtime.h>
#include <math.h>

// Problem constants (b=4, n=m=l=4096, d=512, fft_len=8192, t_len=2l-2=8190)
#define N_FFT   8192
#define SEQ     4096
#define NCH     512
#define TLEN    8190
#define TC_STRIDE 4098   // compact-layout stride (fallback path)

__device__ __forceinline__ float2 cmul(float2 a, float2 b) {
    return make_float2(a.x * b.x - a.y * b.y, a.x * b.y + a.y * b.x);
}
__device__ __forceinline__ float2 cmulj(float2 a, float2 b) {   // a * conj(b)
    return make_float2(a.x * b.x + a.y * b.y, a.y * b.x - a.x * b.y);
}
__device__ __forceinline__ float2 cadd(float2 a, float2 b) {
    return make_float2(a.x + b.x, a.y + b.y);
}
__device__ __forceinline__ float2 csub(float2 a, float2 b) {
    return make_float2(a.x - b.x, a.y - b.y);
}

// W32^j = exp(-2*pi*i*j/32), j in [0,16)
constexpr float W32C[16] = {
    1.0f, 0.9807852804032304f, 0.9238795325112867f, 0.8314696123025452f,
    0.7071067811865476f, 0.5555702330196023f, 0.3826834323650898f, 0.1950903220161283f,
    0.0f, -0.1950903220161282f, -0.3826834323650897f, -0.5555702330196020f,
    -0.7071067811865475f, -0.8314696123025453f, -0.9238795325112867f, -0.9807852804032304f
};
constexpr float W32S[16] = {
    -0.0f, -0.1950903220161283f, -0.3826834323650898f, -0.5555702330196022f,
    -0.7071067811865476f, -0.8314696123025452f, -0.9238795325112867f, -0.9807852804032304f,
    -1.0f, -0.9807852804032304f, -0.9238795325112867f, -0.8314696123025453f,
    -0.7071067811865476f, -0.5555702330196022f, -0.3826834323650899f, -0.1950903220161286f
};

constexpr int BREV5[32] = {0,16,8,24,4,20,12,28,2,18,10,26,6,22,14,30,
                           1,17,9,25,5,21,13,29,3,19,11,27,7,23,15,31};
constexpr int BREV4[16] = {0,8,4,12,2,10,6,14,1,9,5,13,3,11,7,15};
constexpr int BREV3[8]  = {0,4,2,6,1,5,3,7};

__device__ __forceinline__ int brev3i(int b) {
    return ((b & 1) << 2) | (b & 2) | ((b & 4) >> 2);
}

// ---------------------------------------------------------------- reg FFTs ---
// radix-2 DIF, natural in -> a[j] = A[brev(j)]
__device__ __forceinline__ void fft32_dif(float2 a[32]) {
#pragma unroll
    for (int s = 4; s >= 0; --s) {
        const int h = 1 << s;
#pragma unroll
        for (int g = 0; g < 32; g += 2 * h) {
#pragma unroll
            for (int i = 0; i < h; ++i) {
                float2 x0 = a[g + i], x1 = a[g + i + h];
                a[g + i] = cadd(x0, x1);
                float2 w = make_float2(W32C[i << (4 - s)], W32S[i << (4 - s)]);
                a[g + i + h] = cmul(csub(x0, x1), w);
            }
        }
    }
}

__device__ __forceinline__ void fft16_dif(float2 a[16]) {
#pragma unroll
    for (int s = 3; s >= 0; --s) {
        const int h = 1 << s;
#pragma unroll
        for (int g = 0; g < 16; g += 2 * h) {
#pragma unroll
            for (int i = 0; i < h; ++i) {
                float2 x0 = a[g + i], x1 = a[g + i + h];
                a[g + i] = cadd(x0, x1);
                // W_16^{i*2^(3-s)} = W32^{i*2^(4-s)}
                float2 w = make_float2(W32C[i << (4 - s)], W32S[i << (4 - s)]);
                a[g + i + h] = cmul(csub(x0, x1), w);
            }
        }
    }
}

__device__ __forceinline__ void ifft16_dit(float2 a[16]) {
#pragma unroll
    for (int s = 0; s <= 3; ++s) {
        const int h = 1 << s;
#pragma unroll
        for (int g = 0; g < 16; g += 2 * h) {
#pragma unroll
            for (int i = 0; i < h; ++i) {
                float2 w = make_float2(W32C[i << (4 - s)], -W32S[i << (4 - s)]);
                float2 t = cmul(a[g + i + h], w);
                float2 x0 = a[g + i];
                a[g + i] = cadd(x0, t);
                a[g + i + h] = csub(x0, t);
            }
        }
    }
}

__device__ __forceinline__ void fft8_dif(float2 a[8]) {
#pragma unroll
    for (int s = 2; s >= 0; --s) {
        const int h = 1 << s;
#pragma unroll
        for (int g = 0; g < 8; g += 2 * h) {
#pragma unroll
            for (int i = 0; i < h; ++i) {
                float2 x0 = a[g + i], x1 = a[g + i + h];
                a[g + i] = cadd(x0, x1);
                int e = (i << (2 - s)) << 2;   // W8^m = W32^{4m}
                float2 w = make_float2(W32C[e], W32S[e]);
                a[g + i + h] = cmul(csub(x0, x1), w);
            }
        }
    }
}

__device__ __forceinline__ void ifft8_dit(float2 a[8]) {
#pragma unroll
    for (int s = 0; s <= 2; ++s) {
        const int h = 1 << s;
#pragma unroll
        for (int g = 0; g < 8; g += 2 * h) {
#pragma unroll
            for (int i = 0; i < h; ++i) {
                int e = (i << (2 - s)) << 2;
                float2 w = make_float2(W32C[e], -W32S[e]);
                float2 t = cmul(a[g + i + h], w);
                float2 x0 = a[g + i];
                a[g + i] = cadd(x0, t);
                a[g + i + h] = csub(x0, t);
            }
        }
    }
}

// bank-conflict-free LDS slot, 32-row layout (tfft): r in [0,32), c in [0,256)
__device__ __forceinline__ int SLOT(int r, int c) {
    return (r << 8) + (c ^ ((c >> 4) & 7) ^ ((r & 1) << 3));
}
// LDS slot of frequency bin q after tfft forward stage C
__device__ __forceinline__ int ZADDR(int q) {
    return SLOT(q & 31, (((q >> 5) & 31) << 3) + brev3i((q >> 10) & 7));
}
// 16-row layout (conv2): r in [0,16), c in [0,256)
__device__ __forceinline__ int SLOT16(int r, int c) {
    return (r << 8) + (c ^ ((c >> 4) & 7) ^ ((r & 1) << 3));
}

// ---------------------------------------------------------------- twiddles ---
__global__ __launch_bounds__(256) void twiddle_init(float2* __restrict__ tw) {
    int k = blockIdx.x * 256 + threadIdx.x;
    double th = -2.0 * 3.14159265358979323846 * (double)k / (double)N_FFT;
    tw[k] = make_float2((float)cos(th), (float)sin(th));
}

// ---------------------------------------------------------------- t spectra --
// Monolithic 8192 FFT (32x32x8 four-step), channels d0=2*bid, d1=2*bid+1
// packed. Emits per-channel spectrum split by bin parity, in conv2's stage-C
// consumption order: Tc[d][par*4096 + s], s = u*16 + j,
// bin = 2*(k1 + 16*r1 + 256*brev4(j)) + par, k1 = u>>4, r1 = u&15. Prescaled 1/8192.
__global__ __launch_bounds__(256) void tfft2_kernel(const float* __restrict__ t,
                                                    const float2* __restrict__ tw,
                                                    float2* __restrict__ Tc) {
    __shared__ float2 z[N_FFT];
    const int tid = threadIdx.x;
    const int d0 = blockIdx.x * 2;
    const int d1 = d0 + 1;

    float2 a[32];
#pragma unroll
    for (int n1 = 0; n1 < 32; ++n1) {
        int n = (n1 << 8) + tid;
        float va = 0.f, vb = 0.f;
        if (n < TLEN) {
            va = t[(size_t)n * NCH + d0];
            vb = t[(size_t)n * NCH + d1];
        }
        a[n1] = make_float2(va, vb);
    }
    fft32_dif(a);
    {   // twiddle w^k1, w = tw[tid]; even/odd incremental chains
        float2 w = tw[tid], w2 = cmul(w, w);
        float2 we = make_float2(1.f, 0.f), wo = w;
#pragma unroll
        for (int k1 = 0; k1 < 32; k1 += 2) {
            z[SLOT(k1, tid)]     = (k1 == 0) ? a[0] : cmul(a[BREV5[k1]], we);
            z[SLOT(k1 + 1, tid)] = cmul(a[BREV5[k1 + 1]], wo);
            we = cmul(we, w2); wo = cmul(wo, w2);
        }
    }
    __syncthreads();

    {   // step B
        const int r = tid >> 3, n2p = tid & 7;
#pragma unroll
        for (int n1p = 0; n1p < 32; ++n1p)
            a[n1p] = z[SLOT(r, (n1p << 3) + n2p)];
        fft32_dif(a);
        float2 wb = tw[n2p << 5], wb2 = cmul(wb, wb);
        float2 be = make_float2(1.f, 0.f), bo = wb;
#pragma unroll
        for (int k1p = 0; k1p < 32; k1p += 2) {
            z[SLOT(r, (k1p << 3) + n2p)]       = (k1p == 0) ? a[0] : cmul(a[BREV5[k1p]], be);
            z[SLOT(r, ((k1p + 1) << 3) + n2p)] = cmul(a[BREV5[k1p + 1]], bo);
            be = cmul(be, wb2); bo = cmul(bo, wb2);
        }
    }
    __syncthreads();

    // step C: 8-point FFTs
#pragma unroll
    for (int u = 0; u < 4; ++u) {
        int f = tid + (u << 8);
        int k1 = f >> 5, k1p = f & 31;
        float2 b[8];
#pragma unroll
        for (int e = 0; e < 8; ++e) b[e] = z[SLOT(k1, (k1p << 3) + e)];
        fft8_dif(b);
#pragma unroll
        for (int j = 0; j < 8; ++j) z[SLOT(k1, (k1p << 3) + j)] = b[j];
    }
    __syncthreads();

    // Hermitian unpack into parity-split, conv2-order layout
    const float sc = 0.5f / (float)N_FFT;   // fold in ifft 1/N
#pragma unroll
    for (int v = 0; v < 16; ++v) {
        int s = tid + (v << 8);                     // s in [0,4096)
        int k1 = s >> 8, r1 = (s >> 4) & 15, j = s & 15;
        int kp = k1 + (r1 << 4) + (BREV4[j] << 8);  // k' in [0,4096)
#pragma unroll
        for (int par = 0; par < 2; ++par) {
            int k  = 2 * kp + par;
            int km = (N_FFT - k) & (N_FFT - 1);
            float2 A = z[ZADDR(k)];
            float2 B = z[ZADDR(km)];
            float2 Bj = make_float2(B.x, -B.y);
            float2 T0 = make_float2((A.x + Bj.x) * sc, (A.y + Bj.y) * sc);
            float2 dd = csub(A, Bj);
            float2 T1 = make_float2(dd.y * sc, -dd.x * sc);
            Tc[(size_t)d0 * N_FFT + (par << 12) + s] = T0;
            Tc[(size_t)d1 * N_FFT + (par << 12) + s] = T1;
        }
    }
}

// ---------------------------------------------------------------- main conv --
// Even/odd bin split: two 4096-point chains (16x16x16 four-step), 32 KB LDS.
// Chain par=0: U_e = unnorm_ifft(FFT(x) .* Te); par=1 with x*w, To.
// o[n] = U_e[n] + conj(w[n]) * U_o[n], w[n] = tw[n].
__global__ __launch_bounds__(256, 4) void conv2_kernel(const float* __restrict__ x,
                                                       const float2* __restrict__ tw,
                                                       const float2* __restrict__ Tc,
                                                       float* __restrict__ out) {
    __shared__ float2 z[SEQ];          // 16 rows x 256 cols, 32 KB
    const int tid = threadIdx.x;
    // XCD swizzle; consecutive sb pairs share d (T reuse in same XCD's L2)
    const int sb = (blockIdx.x & 7) * 128 + (blockIdx.x >> 3);
    const int d  = sb >> 1;
    const int pb = sb & 1;

    const float* x0 = x + (size_t)(2 * pb) * SEQ * NCH + d;
    const float* x1 = x0 + (size_t)SEQ * NCH;

    float2 a[16];
    float2 ie[16];

#pragma unroll
    for (int par = 0; par < 2; ++par) {
        if (par == 1) __syncthreads();   // protect LDS reuse across chains

        // ---- stage A: load (+modulate for odd), fft16, twiddle, -> LDS
#pragma unroll
        for (int n1 = 0; n1 < 16; ++n1) {
            int n = (n1 << 8) + tid;
            float2 v = make_float2(x0[(size_t)n * NCH], x1[(size_t)n * NCH]);
            if (par == 1) v = cmul(v, tw[n]);        // coalesced tw load
            a[n1] = v;
        }
        fft16_dif(a);
        {
            float2 w = tw[2 * tid];                  // W_4096^tid
            float2 w2 = cmul(w, w);
            float2 we = make_float2(1.f, 0.f), wo = w;
#pragma unroll
            for (int k1 = 0; k1 < 16; k1 += 2) {
                z[SLOT16(k1, tid)]     = (k1 == 0) ? a[0] : cmul(a[BREV4[k1]], we);
                z[SLOT16(k1 + 1, tid)] = cmul(a[BREV4[k1 + 1]], wo);
                we = cmul(we, w2); wo = cmul(wo, w2);
            }
        }
        __syncthreads();

        // ---- stage B: FFT16 over n2 for (k1, n3)
        {
            const int k1 = tid >> 4, n3 = tid & 15;
#pragma unroll
            for (int n2 = 0; n2 < 16; ++n2)
                a[n2] = z[SLOT16(k1, (n2 << 4) + n3)];
            fft16_dif(a);
            float2 wb = tw[n3 << 5];                 // W_256^{n3}
            float2 wb2 = cmul(wb, wb);
            float2 be = make_float2(1.f, 0.f), bo = wb;
#pragma unroll
            for (int r1 = 0; r1 < 16; r1 += 2) {
                z[SLOT16(k1, (r1 << 4) + n3)]       = (r1 == 0) ? a[0] : cmul(a[BREV4[r1]], be);
                z[SLOT16(k1, ((r1 + 1) << 4) + n3)] = cmul(a[BREV4[r1 + 1]], bo);
                be = cmul(be, wb2); bo = cmul(bo, wb2);
            }
        }
        __syncthreads();

        // ---- stage C fwd + pointwise + stage C inverse (fused)
        {
            const int k1 = tid >> 4, r1 = tid & 15;
#pragma unroll
            for (int n3 = 0; n3 < 16; ++n3)
                a[n3] = z[SLOT16(k1, (r1 << 4) + n3)];
            fft16_dif(a);
            // 16 consecutive complex bins, coalesced float4 loads
            const float4* tp = (const float4*)(Tc + ((size_t)d << 13) + (par << 12) + (tid << 4));
#pragma unroll
            for (int q = 0; q < 8; ++q) {
                float4 f4 = tp[q];
                a[2 * q]     = cmul(a[2 * q],     make_float2(f4.x, f4.y));
                a[2 * q + 1] = cmul(a[2 * q + 1], make_float2(f4.z, f4.w));
            }
            ifft16_dit(a);   // DIF output order == DIT input order
#pragma unroll
            for (int n3 = 0; n3 < 16; ++n3)
                z[SLOT16(k1, (r1 << 4) + n3)] = a[n3];
        }
        __syncthreads();

        // ---- stage B inverse
        {
            const int k1 = tid >> 4, n3 = tid & 15;
            float2 wb = tw[n3 << 5], wb2 = cmul(wb, wb);
            float2 be = make_float2(1.f, 0.f), bo = wb;
#pragma unroll
            for (int r1 = 0; r1 < 16; r1 += 2) {
                float2 v0 = z[SLOT16(k1, (r1 << 4) + n3)];
                float2 v1 = z[SLOT16(k1, ((r1 + 1) << 4) + n3)];
                a[BREV4[r1]]     = (r1 == 0) ? v0 : cmulj(v0, be);
                a[BREV4[r1 + 1]] = cmulj(v1, bo);
                be = cmul(be, wb2); bo = cmul(bo, wb2);
            }
            ifft16_dit(a);
#pragma unroll
            for (int n2 = 0; n2 < 16; ++n2)
                z[SLOT16(k1, (n2 << 4) + n3)] = a[n2];
        }
        __syncthreads();

        // ---- stage A inverse (reads only this thread's own column slots)
        {
            float2 w = tw[2 * tid], w2 = cmul(w, w);
            float2 we = make_float2(1.f, 0.f), wo = w;
#pragma unroll
            for (int k1 = 0; k1 < 16; k1 += 2) {
                float2 v0 = z[SLOT16(k1, tid)];
                float2 v1 = z[SLOT16(k1 + 1, tid)];
                a[BREV4[k1]]     = (k1 == 0) ? v0 : cmulj(v0, we);
                a[BREV4[k1 + 1]] = cmulj(v1, wo);
                we = cmul(we, w2); wo = cmul(wo, w2);
            }
            ifft16_dit(a);   // a[n1] = U_par[n1*256 + tid]
        }

        if (par == 0) {
#pragma unroll
            for (int n1 = 0; n1 < 16; ++n1) ie[n1] = a[n1];
        } else {
            float* o0 = out + (size_t)(2 * pb) * SEQ * NCH + d;
            float* o1 = o0 + (size_t)SEQ * NCH;
#pragma unroll
            for (int n1 = 0; n1 < 16; ++n1) {
                int n = (n1 << 8) + tid;
                float2 o = cadd(ie[n1], cmulj(a[n1], tw[n]));
                o0[(size_t)n * NCH] = o.x;
                o1[(size_t)n * NCH] = o.y;
            }
        }
    }
}

// =================== compact fallback path (small ws) =======================
__global__ __launch_bounds__(256) void tfft_compact(const float* __restrict__ t,
                                                    const float2* __restrict__ tw,
                                                    float2* __restrict__ Tc) {
    __shared__ float2 z[N_FFT];
    const int tid = threadIdx.x;
    const int d0 = blockIdx.x * 2;
    const int d1 = d0 + 1;

    float2 a[32];
#pragma unroll
    for (int n1 = 0; n1 < 32; ++n1) {
        int n = (n1 << 8) + tid;
        float va = 0.f, vb = 0.f;
        if (n < TLEN) {
            va = t[(size_t)n * NCH + d0];
            vb = t[(size_t)n * NCH + d1];
        }
        a[n1] = make_float2(va, vb);
    }
    fft32_dif(a);
    {
        float2 w = tw[tid], w2 = cmul(w, w);
        float2 we = make_float2(1.f, 0.f), wo = w;
#pragma unroll
        for (int k1 = 0; k1 < 32; k1 += 2) {
            z[SLOT(k1, tid)]     = (k1 == 0) ? a[0] : cmul(a[BREV5[k1]], we);
            z[SLOT(k1 + 1, tid)] = cmul(a[BREV5[k1 + 1]], wo);
            we = cmul(we, w2); wo = cmul(wo, w2);
        }
    }
    __syncthreads();
    {
        const int r = tid >> 3, n2p = tid & 7;
#pragma unroll
        for (int n1p = 0; n1p < 32; ++n1p)
            a[n1p] = z[SLOT(r, (n1p << 3) + n2p)];
        fft32_dif(a);
        float2 wb = tw[n2p << 5], wb2 = cmul(wb, wb);
        float2 be = make_float2(1.f, 0.f), bo = wb;
#pragma unroll
        for (int k1p = 0; k1p < 32; k1p += 2) {
            z[SLOT(r, (k1p << 3) + n2p)]       = (k1p == 0) ? a[0] : cmul(a[BREV5[k1p]], be);
            z[SLOT(r, ((k1p + 1) << 3) + n2p)] = cmul(a[BREV5[k1p + 1]], bo);
            be = cmul(be, wb2); bo = cmul(bo, wb2);
        }
    }
    __syncthreads();
#pragma unroll
    for (int u = 0; u < 4; ++u) {
        int f = tid + (u << 8);
        int k1 = f >> 5, k1p = f & 31;
        float2 b[8];
#pragma unroll
        for (int e = 0; e < 8; ++e) b[e] = z[SLOT(k1, (k1p << 3) + e)];
        fft8_dif(b);
#pragma unroll
        for (int j = 0; j < 8; ++j) z[SLOT(k1, (k1p << 3) + j)] = b[j];
    }
    __syncthreads();

    const float sc = 0.5f / (float)N_FFT;
    for (int v = 0; v < 17; ++v) {
        int k = tid + (v << 8);
        if (k > SEQ) break;
        int km = (N_FFT - k) & (N_FFT - 1);
        float2 A = z[ZADDR(k)];
        float2 B = z[ZADDR(km)];
        float2 Bj = make_float2(B.x, -B.y);
        float2 T0 = make_float2((A.x + Bj.x) * sc, (A.y + Bj.y) * sc);
        float2 dd = csub(A, Bj);
        float2 T1 = make_float2(dd.y * sc, -dd.x * sc);
        Tc[(size_t)d0 * TC_STRIDE + k] = T0;
        Tc[(size_t)d1 * TC_STRIDE + k] = T1;
    }
}

__global__ __launch_bounds__(256) void conv_compact(const float* __restrict__ x,
                                                    const float2* __restrict__ tw,
                                                    const float2* __restrict__ Tc,
                                                    float* __restrict__ out) {
    __shared__ float2 z[N_FFT];
    const int tid = threadIdx.x;
    const int sb = (blockIdx.x & 7) * 128 + (blockIdx.x >> 3);
    const int d  = sb >> 1;
    const int pb = sb & 1;

    const float* x0 = x + (size_t)(2 * pb) * SEQ * NCH + d;
    const float* x1 = x0 + (size_t)SEQ * NCH;

    float2 a[32];
#pragma unroll
    for (int n1 = 0; n1 < 16; ++n1) {
        int n = (n1 << 8) + tid;
        a[n1] = make_float2(x0[(size_t)n * NCH], x1[(size_t)n * NCH]);
    }
#pragma unroll
    for (int i = 0; i < 16; ++i)
        a[i + 16] = cmul(a[i], make_float2(W32C[i], W32S[i]));
#pragma unroll
    for (int s = 3; s >= 0; --s) {
        const int h = 1 << s;
#pragma unroll
        for (int g = 0; g < 32; g += 2 * h) {
#pragma unroll
            for (int i = 0; i < h; ++i) {
                float2 q0 = a[g + i], q1 = a[g + i + h];
                a[g + i] = cadd(q0, q1);
                float2 w = make_float2(W32C[i << (4 - s)], W32S[i << (4 - s)]);
                a[g + i + h] = cmul(csub(q0, q1), w);
            }
        }
    }
    {
        float2 w = tw[tid], w2 = cmul(w, w);
        float2 we = make_float2(1.f, 0.f), wo = w;
#pragma unroll
        for (int k1 = 0; k1 < 32; k1 += 2) {
            z[SLOT(k1, tid)]     = (k1 == 0) ? a[0] : cmul(a[BREV5[k1]], we);
            z[SLOT(k1 + 1, tid)] = cmul(a[BREV5[k1 + 1]], wo);
            we = cmul(we, w2); wo = cmul(wo, w2);
        }
    }
    __syncthreads();
    {
        const int r = tid >> 3, n2p = tid & 7;
#pragma unroll
        for (int n1p = 0; n1p < 32; ++n1p)
            a[n1p] = z[SLOT(r, (n1p << 3) + n2p)];
        fft32_dif(a);
        float2 wb = tw[n2p << 5], wb2 = cmul(wb, wb);
        float2 be = make_float2(1.f, 0.f), bo = wb;
#pragma unroll
        for (int k1p = 0; k1p < 32; k1p += 2) {
            z[SLOT(r, (k1p << 3) + n2p)]       = (k1p == 0) ? a[0] : cmul(a[BREV5[k1p]], be);
            z[SLOT(r, ((k1p + 1) << 3) + n2p)] = cmul(a[BREV5[k1p + 1]], bo);
            be = cmul(be, wb2); bo = cmul(bo, wb2);
        }
    }
    __syncthreads();
#pragma unroll
    for (int u = 0; u < 4; ++u) {
        int f = tid + (u << 8);
        int k1 = f >> 5, k1p = f & 31;
        float2 b[8];
#pragma unroll
        for (int e = 0; e < 8; ++e) b[e] = z[SLOT(k1, (k1p << 3) + e)];
        fft8_dif(b);
        const float2* Td = Tc + (size_t)d * TC_STRIDE;
#pragma unroll
        for (int j = 0; j < 8; ++j) {
            int k = k1 + (k1p << 5) + (BREV3[j] << 10);
            float2 T;
            if (k <= SEQ) T = Td[k];
            else { T = Td[N_FFT - k]; T.y = -T.y; }
            b[j] = cmul(b[j], T);
        }
        ifft8_dit(b);
#pragma unroll
        for (int e = 0; e < 8; ++e) z[SLOT(k1, (k1p << 3) + e)] = b[e];
    }
    __syncthreads();
    {
        const int r = tid >> 3, n2p = tid & 7;
        float2 wb = tw[n2p << 5], wb2 = cmul(wb, wb);
        float2 be = make_float2(1.f, 0.f), bo = wb;
        float2 aa[32];
#pragma unroll
        for (int k1p = 0; k1p < 32; k1p += 2) {
            float2 v0 = z[SLOT(r, (k1p << 3) + n2p)];
            float2 v1 = z[SLOT(r, ((k1p + 1) << 3) + n2p)];
            aa[BREV5[k1p]]     = (k1p == 0) ? v0 : cmulj(v0, be);
            aa[BREV5[k1p + 1]] = cmulj(v1, bo);
            be = cmul(be, wb2); bo = cmul(bo, wb2);
        }
#pragma unroll
        for (int s = 0; s <= 4; ++s) {
            const int h = 1 << s;
#pragma unroll
            for (int g = 0; g < 32; g += 2 * h) {
#pragma unroll
                for (int i = 0; i < h; ++i) {
                    float2 w = make_float2(W32C[i << (4 - s)], -W32S[i << (4 - s)]);
                    float2 tt = cmul(aa[g + i + h], w);
                    float2 q0 = aa[g + i];
                    aa[g + i] = cadd(q0, tt);
                    aa[g + i + h] = csub(q0, tt);
                }
            }
        }
#pragma unroll
        for (int n1p = 0; n1p < 32; ++n1p)
            z[SLOT(r, (n1p << 3) + n2p)] = aa[n1p];
    }
    __syncthreads();
    {
        float2 w = tw[tid], w2 = cmul(w, w);
        float2 we = make_float2(1.f, 0.f), wo = w;
#pragma unroll
        for (int k1 = 0; k1 < 32; k1 += 2) {
            float2 v0 = z[SLOT(k1, tid)];
            float2 v1 = z[SLOT(k1 + 1, tid)];
            a[BREV5[k1]]     = (k1 == 0) ? v0 : cmulj(v0, we);
            a[BREV5[k1 + 1]] = cmulj(v1, wo);
            we = cmul(we, w2); wo = cmul(wo, w2);
        }
        fft32_dif(a);   // placeholder to keep symmetry; replaced below
    }
    // NOTE: fallback path retains round-3 numerics via full inverse:
    {
        // redo inverse properly (fft32_dif above was wrong direction): reload
        float2 w = tw[tid], w2 = cmul(w, w);
        float2 we = make_float2(1.f, 0.f), wo = w;
#pragma unroll
        for (int k1 = 0; k1 < 32; k1 += 2) {
            float2 v0 = z[SLOT(k1, tid)];
            float2 v1 = z[SLOT(k1 + 1, tid)];
            a[BREV5[k1]]     = (k1 == 0) ? v0 : cmulj(v0, we);
            a[BREV5[k1 + 1]] = cmulj(v1, wo);
            we = cmul(we, w2); wo = cmul(wo, w2);
        }
#pragma unroll
        for (int s = 0; s <= 4; ++s) {
            const int h = 1 << s;
#pragma unroll
            for (int g = 0; g < 32; g += 2 * h) {
#pragma unroll
                for (int i = 0; i < h; ++i) {
                    float2 w3 = make_float2(W32C[i << (4 - s)], -W32S[i << (4 - s)]);
                    float2 tt = cmul(a[g + i + h], w3);
                    float2 q0 = a[g + i];
                    a[g + i] = cadd(q0, tt);
                    a[g + i + h] = csub(q0, tt);
                }
            }
        }
        float* o0 = out + (size_t)(2 * pb) * SEQ * NCH + d;
        float* o1 = o0 + (size_t)SEQ * NCH;
#pragma unroll
        for (int n1 = 0; n1 < 16; ++n1) {
            int n = (n1 << 8) + tid;
            o0[(size_t)n * NCH] = a[n1].x;
            o1[(size_t)n * NCH] = a[n1].y;
        }
    }
}

extern "C" void kernel_launch(void* const* d_in, const int* in_sizes, int n_in,
                              void* d_out, int out_size, void* d_ws, size_t ws_size,
                              hipStream_t stream) {
    (void)in_sizes; (void)n_in; (void)out_size;
    const float* x = (const float*)d_in[0];
    const float* t = (const float*)d_in[1];
    float* out = (float*)d_out;

    float2* tw = (float2*)d_ws;            // 8192 complex = 64 KB
    float2* Tc = tw + N_FFT;

    const size_t need_full = sizeof(float2) * (size_t)N_FFT
                           + sizeof(float2) * (size_t)NCH * N_FFT;   // ~33.6 MB

    twiddle_init<<<N_FFT / 256, 256, 0, stream>>>(tw);
    if (ws_size >= need_full) {
        tfft2_kernel<<<NCH / 2, 256, 0, stream>>>(t, tw, Tc);
        conv2_kernel<<<1024, 256, 0, stream>>>(x, tw, Tc, out);
    } else {
        tfft_compact<<<NCH / 2, 256, 0, stream>>>(t, tw, Tc);
        conv_compact<<<1024, 256, 0, stream>>>(x, tw, Tc, out);
    }
}

// Round 5
// 150.664 us; speedup vs baseline: 1.2041x; 1.2041x over previous
//
#include <hip/hip_runtime.h>
#include <math.h>

// Problem constants (b=4, n=m=l=4096, d=512, fft_len=8192, t_len=2l-2=8190)
#define N_FFT   8192
#define SEQ     4096
#define NCH     512
#define TLEN    8190

__device__ __forceinline__ float2 cmul(float2 a, float2 b) {
    return make_float2(a.x * b.x - a.y * b.y, a.x * b.y + a.y * b.x);
}
__device__ __forceinline__ float2 cmulj(float2 a, float2 b) {   // a * conj(b)
    return make_float2(a.x * b.x + a.y * b.y, a.y * b.x - a.x * b.y);
}
__device__ __forceinline__ float2 cadd(float2 a, float2 b) {
    return make_float2(a.x + b.x, a.y + b.y);
}
__device__ __forceinline__ float2 csub(float2 a, float2 b) {
    return make_float2(a.x - b.x, a.y - b.y);
}

// W32^j = exp(-2*pi*i*j/32), j in [0,16)
constexpr float W32C[16] = {
    1.0f, 0.9807852804032304f, 0.9238795325112867f, 0.8314696123025452f,
    0.7071067811865476f, 0.5555702330196023f, 0.3826834323650898f, 0.1950903220161283f,
    0.0f, -0.1950903220161282f, -0.3826834323650897f, -0.5555702330196020f,
    -0.7071067811865475f, -0.8314696123025453f, -0.9238795325112867f, -0.9807852804032304f
};
constexpr float W32S[16] = {
    -0.0f, -0.1950903220161283f, -0.3826834323650898f, -0.5555702330196022f,
    -0.7071067811865476f, -0.8314696123025452f, -0.9238795325112867f, -0.9807852804032304f,
    -1.0f, -0.9807852804032304f, -0.9238795325112867f, -0.8314696123025453f,
    -0.7071067811865476f, -0.5555702330196022f, -0.3826834323650899f, -0.1950903220161286f
};

constexpr int BREV5[32] = {0,16,8,24,4,20,12,28,2,18,10,26,6,22,14,30,
                           1,17,9,25,5,21,13,29,3,19,11,27,7,23,15,31};
constexpr int BREV4[16] = {0,8,4,12,2,10,6,14,1,9,5,13,3,11,7,15};

__device__ __forceinline__ int brev3i(int b) {
    return ((b & 1) << 2) | (b & 2) | ((b & 4) >> 2);
}

// ---------------------------------------------------------------- reg FFTs ---
__device__ __forceinline__ void fft32_dif(float2 a[32]) {
#pragma unroll
    for (int s = 4; s >= 0; --s) {
        const int h = 1 << s;
#pragma unroll
        for (int g = 0; g < 32; g += 2 * h) {
#pragma unroll
            for (int i = 0; i < h; ++i) {
                float2 x0 = a[g + i], x1 = a[g + i + h];
                a[g + i] = cadd(x0, x1);
                float2 w = make_float2(W32C[i << (4 - s)], W32S[i << (4 - s)]);
                a[g + i + h] = cmul(csub(x0, x1), w);
            }
        }
    }
}

__device__ __forceinline__ void fft16_dif(float2 a[16]) {
#pragma unroll
    for (int s = 3; s >= 0; --s) {
        const int h = 1 << s;
#pragma unroll
        for (int g = 0; g < 16; g += 2 * h) {
#pragma unroll
            for (int i = 0; i < h; ++i) {
                float2 x0 = a[g + i], x1 = a[g + i + h];
                a[g + i] = cadd(x0, x1);
                float2 w = make_float2(W32C[i << (4 - s)], W32S[i << (4 - s)]);
                a[g + i + h] = cmul(csub(x0, x1), w);
            }
        }
    }
}

__device__ __forceinline__ void ifft16_dit(float2 a[16]) {
#pragma unroll
    for (int s = 0; s <= 3; ++s) {
        const int h = 1 << s;
#pragma unroll
        for (int g = 0; g < 16; g += 2 * h) {
#pragma unroll
            for (int i = 0; i < h; ++i) {
                float2 w = make_float2(W32C[i << (4 - s)], -W32S[i << (4 - s)]);
                float2 t = cmul(a[g + i + h], w);
                float2 x0 = a[g + i];
                a[g + i] = cadd(x0, t);
                a[g + i + h] = csub(x0, t);
            }
        }
    }
}

__device__ __forceinline__ void fft8_dif(float2 a[8]) {
#pragma unroll
    for (int s = 2; s >= 0; --s) {
        const int h = 1 << s;
#pragma unroll
        for (int g = 0; g < 8; g += 2 * h) {
#pragma unroll
            for (int i = 0; i < h; ++i) {
                float2 x0 = a[g + i], x1 = a[g + i + h];
                a[g + i] = cadd(x0, x1);
                int e = (i << (2 - s)) << 2;   // W8^m = W32^{4m}
                float2 w = make_float2(W32C[e], W32S[e]);
                a[g + i + h] = cmul(csub(x0, x1), w);
            }
        }
    }
}

// bank-conflict-reduced LDS slot, 32-row layout (tfft)
__device__ __forceinline__ int SLOT(int r, int c) {
    return (r << 8) + (c ^ ((c >> 4) & 7) ^ ((r & 1) << 3));
}
// LDS slot of frequency bin q after tfft forward stage C
__device__ __forceinline__ int ZADDR(int q) {
    return SLOT(q & 31, (((q >> 5) & 31) << 3) + brev3i((q >> 10) & 7));
}
// 16-row layout (conv)
__device__ __forceinline__ int SLOT16(int r, int c) {
    return (r << 8) + (c ^ ((c >> 4) & 7) ^ ((r & 1) << 3));
}

// ---------------------------------------------------------------- twiddles ---
__global__ __launch_bounds__(256) void twiddle_init(float2* __restrict__ tw) {
    int k = blockIdx.x * 256 + threadIdx.x;
    double th = -2.0 * 3.14159265358979323846 * (double)k / (double)N_FFT;
    tw[k] = make_float2((float)cos(th), (float)sin(th));
}

// ---------------------------------------------------------------- t spectra --
// Monolithic 8192 FFT (32x32x8 four-step), channels d0=2*bid, d1=2*bid+1
// packed. Emits per-channel spectrum split by bin parity, in conv's stage-C
// consumption order: Tc[d][par*4096 + s], bin = 2*(k1+16*r1+256*brev4(j))+par
// with s = (k1<<8)+(r1<<4)+j. Prescaled by 1/8192.
__global__ __launch_bounds__(256) void tfft2_kernel(const float* __restrict__ t,
                                                    const float2* __restrict__ tw,
                                                    float2* __restrict__ Tc) {
    __shared__ float2 z[N_FFT];
    const int tid = threadIdx.x;
    const int d0 = blockIdx.x * 2;
    const int d1 = d0 + 1;

    float2 a[32];
#pragma unroll
    for (int n1 = 0; n1 < 32; ++n1) {
        int n = (n1 << 8) + tid;
        float va = 0.f, vb = 0.f;
        if (n < TLEN) {
            va = t[(size_t)n * NCH + d0];
            vb = t[(size_t)n * NCH + d1];
        }
        a[n1] = make_float2(va, vb);
    }
    fft32_dif(a);
    {   // twiddle w^k1, w = tw[tid]; even/odd incremental chains
        float2 w = tw[tid], w2 = cmul(w, w);
        float2 we = make_float2(1.f, 0.f), wo = w;
#pragma unroll
        for (int k1 = 0; k1 < 32; k1 += 2) {
            z[SLOT(k1, tid)]     = (k1 == 0) ? a[0] : cmul(a[BREV5[k1]], we);
            z[SLOT(k1 + 1, tid)] = cmul(a[BREV5[k1 + 1]], wo);
            we = cmul(we, w2); wo = cmul(wo, w2);
        }
    }
    __syncthreads();

    {   // step B
        const int r = tid >> 3, n2p = tid & 7;
#pragma unroll
        for (int n1p = 0; n1p < 32; ++n1p)
            a[n1p] = z[SLOT(r, (n1p << 3) + n2p)];
        fft32_dif(a);
        float2 wb = tw[n2p << 5], wb2 = cmul(wb, wb);
        float2 be = make_float2(1.f, 0.f), bo = wb;
#pragma unroll
        for (int k1p = 0; k1p < 32; k1p += 2) {
            z[SLOT(r, (k1p << 3) + n2p)]       = (k1p == 0) ? a[0] : cmul(a[BREV5[k1p]], be);
            z[SLOT(r, ((k1p + 1) << 3) + n2p)] = cmul(a[BREV5[k1p + 1]], bo);
            be = cmul(be, wb2); bo = cmul(bo, wb2);
        }
    }
    __syncthreads();

    // step C: 8-point FFTs
#pragma unroll
    for (int u = 0; u < 4; ++u) {
        int f = tid + (u << 8);
        int k1 = f >> 5, k1p = f & 31;
        float2 b[8];
#pragma unroll
        for (int e = 0; e < 8; ++e) b[e] = z[SLOT(k1, (k1p << 3) + e)];
        fft8_dif(b);
#pragma unroll
        for (int j = 0; j < 8; ++j) z[SLOT(k1, (k1p << 3) + j)] = b[j];
    }
    __syncthreads();

    // Hermitian unpack into parity-split, conv-order layout
    const float sc = 0.5f / (float)N_FFT;   // fold in ifft 1/N
#pragma unroll
    for (int v = 0; v < 16; ++v) {
        int s = tid + (v << 8);                     // s in [0,4096)
        int k1 = s >> 8, r1 = (s >> 4) & 15, j = s & 15;
        int kp = k1 + (r1 << 4) + (BREV4[j] << 8);  // k' in [0,4096)
#pragma unroll
        for (int par = 0; par < 2; ++par) {
            int k  = 2 * kp + par;
            int km = (N_FFT - k) & (N_FFT - 1);
            float2 A = z[ZADDR(k)];
            float2 B = z[ZADDR(km)];
            float2 Bj = make_float2(B.x, -B.y);
            float2 T0 = make_float2((A.x + Bj.x) * sc, (A.y + Bj.y) * sc);
            float2 dd = csub(A, Bj);
            float2 T1 = make_float2(dd.y * sc, -dd.x * sc);
            Tc[(size_t)d0 * N_FFT + (par << 12) + s] = T0;
            Tc[(size_t)d1 * N_FFT + (par << 12) + s] = T1;
        }
    }
}

// ---------------------------------------------------------------- main conv --
// Even/odd bin split: two 4096-point chains (16x16x16 four-step), 32 KB LDS.
// x held in registers across both chains (single strided read of x).
// OT=1: write combined result to oT[pb][d][n] (contiguous, coalesced);
// OT=0: direct strided write to out.
template<bool OT>
__global__ __launch_bounds__(256, 4) void conv3_kernel(const float* __restrict__ x,
                                                       const float2* __restrict__ tw,
                                                       const float2* __restrict__ Tc,
                                                       float2* __restrict__ oT,
                                                       float* __restrict__ out) {
    __shared__ float2 z[SEQ];          // 16 rows x 256 cols, 32 KB
    const int tid = threadIdx.x;
    // XCD swizzle; consecutive sb pairs share d (T reuse in same XCD's L2)
    const int sb = (blockIdx.x & 7) * 128 + (blockIdx.x >> 3);
    const int d  = sb >> 1;
    const int pb = sb & 1;

    const float* x0 = x + (size_t)(2 * pb) * SEQ * NCH + d;
    const float* x1 = x0 + (size_t)SEQ * NCH;

    float2 xr[16], a[16], ie[16];

    // single strided read of x (lines shared with neighboring-d blocks via L2)
#pragma unroll
    for (int n1 = 0; n1 < 16; ++n1) {
        int n = (n1 << 8) + tid;
        xr[n1] = make_float2(x0[(size_t)n * NCH], x1[(size_t)n * NCH]);
    }

#pragma unroll
    for (int par = 0; par < 2; ++par) {
        if (par == 1) __syncthreads();   // protect LDS reuse across chains

        // ---- stage A: regs (+modulate for odd), fft16, twiddle, -> LDS
        if (par == 0) {
#pragma unroll
            for (int n1 = 0; n1 < 16; ++n1) a[n1] = xr[n1];
        } else {
#pragma unroll
            for (int n1 = 0; n1 < 16; ++n1) {
                int n = (n1 << 8) + tid;
                a[n1] = cmul(xr[n1], tw[n]);         // coalesced tw load
            }
        }
        fft16_dif(a);
        {
            float2 w = tw[2 * tid];                  // W_4096^tid
            float2 w2 = cmul(w, w);
            float2 we = make_float2(1.f, 0.f), wo = w;
#pragma unroll
            for (int k1 = 0; k1 < 16; k1 += 2) {
                z[SLOT16(k1, tid)]     = (k1 == 0) ? a[0] : cmul(a[BREV4[k1]], we);
                z[SLOT16(k1 + 1, tid)] = cmul(a[BREV4[k1 + 1]], wo);
                we = cmul(we, w2); wo = cmul(wo, w2);
            }
        }
        __syncthreads();

        // ---- stage B: FFT16 over n2 for (k1, n3)
        {
            const int k1 = tid >> 4, n3 = tid & 15;
#pragma unroll
            for (int n2 = 0; n2 < 16; ++n2)
                a[n2] = z[SLOT16(k1, (n2 << 4) + n3)];
            fft16_dif(a);
            float2 wb = tw[n3 << 5];                 // W_256^{n3}
            float2 wb2 = cmul(wb, wb);
            float2 be = make_float2(1.f, 0.f), bo = wb;
#pragma unroll
            for (int r1 = 0; r1 < 16; r1 += 2) {
                z[SLOT16(k1, (r1 << 4) + n3)]       = (r1 == 0) ? a[0] : cmul(a[BREV4[r1]], be);
                z[SLOT16(k1, ((r1 + 1) << 4) + n3)] = cmul(a[BREV4[r1 + 1]], bo);
                be = cmul(be, wb2); bo = cmul(bo, wb2);
            }
        }
        __syncthreads();

        // ---- stage C fwd + pointwise + stage C inverse (fused)
        {
            const int k1 = tid >> 4, r1 = tid & 15;
#pragma unroll
            for (int n3 = 0; n3 < 16; ++n3)
                a[n3] = z[SLOT16(k1, (r1 << 4) + n3)];
            fft16_dif(a);
            const float4* tp = (const float4*)(Tc + ((size_t)d << 13) + (par << 12) + (tid << 4));
#pragma unroll
            for (int q = 0; q < 8; ++q) {
                float4 f4 = tp[q];
                a[2 * q]     = cmul(a[2 * q],     make_float2(f4.x, f4.y));
                a[2 * q + 1] = cmul(a[2 * q + 1], make_float2(f4.z, f4.w));
            }
            ifft16_dit(a);   // DIF output order == DIT input order
#pragma unroll
            for (int n3 = 0; n3 < 16; ++n3)
                z[SLOT16(k1, (r1 << 4) + n3)] = a[n3];
        }
        __syncthreads();

        // ---- stage B inverse
        {
            const int k1 = tid >> 4, n3 = tid & 15;
            float2 wb = tw[n3 << 5], wb2 = cmul(wb, wb);
            float2 be = make_float2(1.f, 0.f), bo = wb;
#pragma unroll
            for (int r1 = 0; r1 < 16; r1 += 2) {
                float2 v0 = z[SLOT16(k1, (r1 << 4) + n3)];
                float2 v1 = z[SLOT16(k1, ((r1 + 1) << 4) + n3)];
                a[BREV4[r1]]     = (r1 == 0) ? v0 : cmulj(v0, be);
                a[BREV4[r1 + 1]] = cmulj(v1, bo);
                be = cmul(be, wb2); bo = cmul(bo, wb2);
            }
            ifft16_dit(a);
#pragma unroll
            for (int n2 = 0; n2 < 16; ++n2)
                z[SLOT16(k1, (n2 << 4) + n3)] = a[n2];
        }
        __syncthreads();

        // ---- stage A inverse (thread-private column slots)
        {
            float2 w = tw[2 * tid], w2 = cmul(w, w);
            float2 we = make_float2(1.f, 0.f), wo = w;
#pragma unroll
            for (int k1 = 0; k1 < 16; k1 += 2) {
                float2 v0 = z[SLOT16(k1, tid)];
                float2 v1 = z[SLOT16(k1 + 1, tid)];
                a[BREV4[k1]]     = (k1 == 0) ? v0 : cmulj(v0, we);
                a[BREV4[k1 + 1]] = cmulj(v1, wo);
                we = cmul(we, w2); wo = cmul(wo, w2);
            }
            ifft16_dit(a);   // a[n1] = U_par[n1*256 + tid]
        }

        if (par == 0) {
#pragma unroll
            for (int n1 = 0; n1 < 16; ++n1) ie[n1] = a[n1];
        } else {
            if constexpr (OT) {
                float2* op = oT + (((size_t)(pb * NCH + d)) << 12);
#pragma unroll
                for (int n1 = 0; n1 < 16; ++n1) {
                    int n = (n1 << 8) + tid;
                    op[n] = cadd(ie[n1], cmulj(a[n1], tw[n]));   // coalesced 8B
                }
            } else {
                float* o0 = out + (size_t)(2 * pb) * SEQ * NCH + d;
                float* o1 = o0 + (size_t)SEQ * NCH;
#pragma unroll
                for (int n1 = 0; n1 < 16; ++n1) {
                    int n = (n1 << 8) + tid;
                    float2 o = cadd(ie[n1], cmulj(a[n1], tw[n]));
                    o0[(size_t)n * NCH] = o.x;
                    o1[(size_t)n * NCH] = o.y;
                }
            }
        }
    }
}

// ---------------------------------------------------------------- transpose --
// oT[pb][d][n] (float2: {b=2pb, b=2pb+1}) -> out[b][n][d]. LDS-tiled 32d x 64n.
__global__ __launch_bounds__(256) void transpose_out(const float2* __restrict__ oT,
                                                     float* __restrict__ out) {
    __shared__ float2 tile[32][65];
    const int tid = threadIdx.x;
    const int bid = blockIdx.x;
    const int pb = bid >> 10;
    const int dt = (bid >> 6) & 15;
    const int nt = bid & 63;
    const int d0 = dt << 5, n0 = nt << 6;

    {
        const int nl = tid & 63, dl = tid >> 6;
#pragma unroll
        for (int i = 0; i < 8; ++i) {
            int dd = dl + (i << 2);
            tile[dd][nl] = oT[(((size_t)(pb * NCH + d0 + dd)) << 12) + n0 + nl];
        }
    }
    __syncthreads();
    {
        const int dl = tid & 31, ns = tid >> 5;
        float* o0 = out + (size_t)(2 * pb) * SEQ * NCH;
        float* o1 = o0 + (size_t)SEQ * NCH;
#pragma unroll
        for (int j = 0; j < 8; ++j) {
            int nn = n0 + ns + (j << 3);
            float2 v = tile[dl][ns + (j << 3)];
            o0[(size_t)nn * NCH + d0 + dl] = v.x;   // 128B contiguous per 32 lanes
            o1[(size_t)nn * NCH + d0 + dl] = v.y;
        }
    }
}

extern "C" void kernel_launch(void* const* d_in, const int* in_sizes, int n_in,
                              void* d_out, int out_size, void* d_ws, size_t ws_size,
                              hipStream_t stream) {
    (void)in_sizes; (void)n_in; (void)out_size;
    const float* x = (const float*)d_in[0];
    const float* t = (const float*)d_in[1];
    float* out = (float*)d_out;

    float2* tw = (float2*)d_ws;                    // 8192 float2 = 64 KB
    float2* Tc = tw + N_FFT;                       // 512*8192 float2 = 33.55 MB
    float2* oT = Tc + (size_t)NCH * N_FFT;         // 2*512*4096 float2 = 33.55 MB

    const size_t need_ot = sizeof(float2) * ((size_t)N_FFT + (size_t)NCH * N_FFT
                                             + 2ull * NCH * SEQ);   // ~67.2 MB

    twiddle_init<<<N_FFT / 256, 256, 0, stream>>>(tw);
    tfft2_kernel<<<NCH / 2, 256, 0, stream>>>(t, tw, Tc);
    if (ws_size >= need_ot) {
        conv3_kernel<true><<<1024, 256, 0, stream>>>(x, tw, Tc, oT, out);
        transpose_out<<<2048, 256, 0, stream>>>(oT, out);
    } else {
        conv3_kernel<false><<<1024, 256, 0, stream>>>(x, tw, Tc, nullptr, out);
    }
}

// Round 6
// 134.810 us; speedup vs baseline: 1.3457x; 1.1176x over previous
//
#include <hip/hip_runtime.h>
#include <math.h>

// Problem constants (b=4, n=m=l=4096, d=512, fft_len=8192, t_len=2l-2=8190)
#define N_FFT   8192
#define SEQ     4096
#define NCH     512
#define TLEN    8190

__device__ __forceinline__ float2 cmul(float2 a, float2 b) {
    return make_float2(a.x * b.x - a.y * b.y, a.x * b.y + a.y * b.x);
}
__device__ __forceinline__ float2 cmulj(float2 a, float2 b) {   // a * conj(b)
    return make_float2(a.x * b.x + a.y * b.y, a.y * b.x - a.x * b.y);
}
__device__ __forceinline__ float2 cadd(float2 a, float2 b) {
    return make_float2(a.x + b.x, a.y + b.y);
}
__device__ __forceinline__ float2 csub(float2 a, float2 b) {
    return make_float2(a.x - b.x, a.y - b.y);
}

// W32^j = exp(-2*pi*i*j/32), j in [0,16)
constexpr float W32C[16] = {
    1.0f, 0.9807852804032304f, 0.9238795325112867f, 0.8314696123025452f,
    0.7071067811865476f, 0.5555702330196023f, 0.3826834323650898f, 0.1950903220161283f,
    0.0f, -0.1950903220161282f, -0.3826834323650897f, -0.5555702330196020f,
    -0.7071067811865475f, -0.8314696123025453f, -0.9238795325112867f, -0.9807852804032304f
};
constexpr float W32S[16] = {
    -0.0f, -0.1950903220161283f, -0.3826834323650898f, -0.5555702330196022f,
    -0.7071067811865476f, -0.8314696123025452f, -0.9238795325112867f, -0.9807852804032304f,
    -1.0f, -0.9807852804032304f, -0.9238795325112867f, -0.8314696123025453f,
    -0.7071067811865476f, -0.5555702330196022f, -0.3826834323650899f, -0.1950903220161286f
};

constexpr int BREV5[32] = {0,16,8,24,4,20,12,28,2,18,10,26,6,22,14,30,
                           1,17,9,25,5,21,13,29,3,19,11,27,7,23,15,31};
constexpr int BREV4[16] = {0,8,4,12,2,10,6,14,1,9,5,13,3,11,7,15};

__device__ __forceinline__ int brev3i(int b) {
    return ((b & 1) << 2) | (b & 2) | ((b & 4) >> 2);
}

// ---------------------------------------------------------------- reg FFTs ---
__device__ __forceinline__ void fft32_dif(float2 a[32]) {
#pragma unroll
    for (int s = 4; s >= 0; --s) {
        const int h = 1 << s;
#pragma unroll
        for (int g = 0; g < 32; g += 2 * h) {
#pragma unroll
            for (int i = 0; i < h; ++i) {
                float2 x0 = a[g + i], x1 = a[g + i + h];
                a[g + i] = cadd(x0, x1);
                float2 w = make_float2(W32C[i << (4 - s)], W32S[i << (4 - s)]);
                a[g + i + h] = cmul(csub(x0, x1), w);
            }
        }
    }
}

__device__ __forceinline__ void fft16_dif(float2 a[16]) {
#pragma unroll
    for (int s = 3; s >= 0; --s) {
        const int h = 1 << s;
#pragma unroll
        for (int g = 0; g < 16; g += 2 * h) {
#pragma unroll
            for (int i = 0; i < h; ++i) {
                float2 x0 = a[g + i], x1 = a[g + i + h];
                a[g + i] = cadd(x0, x1);
                float2 w = make_float2(W32C[i << (4 - s)], W32S[i << (4 - s)]);
                a[g + i + h] = cmul(csub(x0, x1), w);
            }
        }
    }
}

__device__ __forceinline__ void ifft16_dit(float2 a[16]) {
#pragma unroll
    for (int s = 0; s <= 3; ++s) {
        const int h = 1 << s;
#pragma unroll
        for (int g = 0; g < 16; g += 2 * h) {
#pragma unroll
            for (int i = 0; i < h; ++i) {
                float2 w = make_float2(W32C[i << (4 - s)], -W32S[i << (4 - s)]);
                float2 t = cmul(a[g + i + h], w);
                float2 x0 = a[g + i];
                a[g + i] = cadd(x0, t);
                a[g + i + h] = csub(x0, t);
            }
        }
    }
}

__device__ __forceinline__ void fft8_dif(float2 a[8]) {
#pragma unroll
    for (int s = 2; s >= 0; --s) {
        const int h = 1 << s;
#pragma unroll
        for (int g = 0; g < 8; g += 2 * h) {
#pragma unroll
            for (int i = 0; i < h; ++i) {
                float2 x0 = a[g + i], x1 = a[g + i + h];
                a[g + i] = cadd(x0, x1);
                int e = (i << (2 - s)) << 2;   // W8^m = W32^{4m}
                float2 w = make_float2(W32C[e], W32S[e]);
                a[g + i + h] = cmul(csub(x0, x1), w);
            }
        }
    }
}

// bank-conflict-reduced LDS slot, 32-row layout (tfft)
__device__ __forceinline__ int SLOT(int r, int c) {
    return (r << 8) + (c ^ ((c >> 4) & 7) ^ ((r & 1) << 3));
}
// LDS slot of frequency bin q after tfft forward stage C
__device__ __forceinline__ int ZADDR(int q) {
    return SLOT(q & 31, (((q >> 5) & 31) << 3) + brev3i((q >> 10) & 7));
}
// 16-row layout (conv)
__device__ __forceinline__ int SLOT16(int r, int c) {
    return (r << 8) + (c ^ ((c >> 4) & 7) ^ ((r & 1) << 3));
}

// ---------------------------------------------------------------- twiddles ---
__global__ __launch_bounds__(256) void twiddle_init(float2* __restrict__ tw) {
    int k = blockIdx.x * 256 + threadIdx.x;
    double th = -2.0 * 3.14159265358979323846 * (double)k / (double)N_FFT;
    tw[k] = make_float2((float)cos(th), (float)sin(th));
}

// ---------------------------------------------------------------- transposes -
// x[b][n][d] -> xT[pb][d][n], float2 = (x[2pb,n,d], x[2pb+1,n,d]).
// Tiles 64n x 64d; both global phases fully coalesced; LDS conflict-free.
__global__ __launch_bounds__(256) void transpose_x(const float* __restrict__ x,
                                                   float2* __restrict__ xT) {
    __shared__ float tX[64][65], tY[64][65];
    const int tid = threadIdx.x;
    const int bid = blockIdx.x;            // [pb:2][dt:8][nt:64]
    const int pb = bid >> 9;
    const int dt = (bid >> 6) & 7;
    const int nt = bid & 63;
    const int d0 = dt << 6, n0 = nt << 6;
    const float* x0 = x + (size_t)(2 * pb) * SEQ * NCH;
    const float* x1 = x0 + (size_t)SEQ * NCH;
    {
        const int c = tid & 63, r4 = tid >> 6;
#pragma unroll
        for (int it = 0; it < 16; ++it) {
            int row = r4 + (it << 2);
            size_t off = (size_t)(n0 + row) * NCH + d0 + c;
            tX[row][c] = x0[off];
            tY[row][c] = x1[off];
        }
    }
    __syncthreads();
    {
        const int nc = tid & 63, dr4 = tid >> 6;
#pragma unroll
        for (int it = 0; it < 16; ++it) {
            int dr = dr4 + (it << 2);
            xT[(((size_t)(pb * NCH + d0 + dr)) << 12) + n0 + nc] =
                make_float2(tX[nc][dr], tY[nc][dr]);
        }
    }
}

// t[n][d] -> tT[dp][n] (n zero-padded to 8192), float2 = (t[n,2dp], t[n,2dp+1])
__global__ __launch_bounds__(256) void transpose_t(const float* __restrict__ t,
                                                   float2* __restrict__ tT) {
    __shared__ float tX[64][65], tY[64][65];
    const int tid = threadIdx.x;
    const int bid = blockIdx.x;            // [nt:128][dpt:4]
    const int nt = bid >> 2, dpt = bid & 3;
    const int n0 = nt << 6, dp0 = dpt << 6;
    {
        const int c = tid & 63, r4 = tid >> 6;
#pragma unroll
        for (int it = 0; it < 16; ++it) {
            int row = r4 + (it << 2);
            int nn = n0 + row;
            float2 v = make_float2(0.f, 0.f);
            if (nn < TLEN)
                v = *(const float2*)(t + (size_t)nn * NCH + ((dp0 + c) << 1));
            tX[row][c] = v.x;
            tY[row][c] = v.y;
        }
    }
    __syncthreads();
    {
        const int nc = tid & 63, dr4 = tid >> 6;
#pragma unroll
        for (int it = 0; it < 16; ++it) {
            int dr = dr4 + (it << 2);
            tT[(((size_t)(dp0 + dr)) << 13) + n0 + nc] =
                make_float2(tX[nc][dr], tY[nc][dr]);
        }
    }
}

// ---------------------------------------------------------------- t spectra --
// Monolithic 8192 FFT (32x32x8), channels d0=2*bid, d1=2*bid+1 packed, input
// from tT (coalesced). Emits parity-split spectrum in conv stage-C order,
// prescaled by 1/8192.
__global__ __launch_bounds__(256) void tfft3_kernel(const float2* __restrict__ tT,
                                                    const float2* __restrict__ tw,
                                                    float2* __restrict__ Tc) {
    __shared__ float2 z[N_FFT];
    const int tid = threadIdx.x;
    const int d0 = blockIdx.x * 2;
    const int d1 = d0 + 1;
    const float2* tp = tT + ((size_t)blockIdx.x << 13);

    float2 a[32];
#pragma unroll
    for (int n1 = 0; n1 < 32; ++n1)
        a[n1] = tp[(n1 << 8) + tid];
    fft32_dif(a);
    {   // twiddle w^k1, w = tw[tid]; even/odd incremental chains
        float2 w = tw[tid], w2 = cmul(w, w);
        float2 we = make_float2(1.f, 0.f), wo = w;
#pragma unroll
        for (int k1 = 0; k1 < 32; k1 += 2) {
            z[SLOT(k1, tid)]     = (k1 == 0) ? a[0] : cmul(a[BREV5[k1]], we);
            z[SLOT(k1 + 1, tid)] = cmul(a[BREV5[k1 + 1]], wo);
            we = cmul(we, w2); wo = cmul(wo, w2);
        }
    }
    __syncthreads();

    {   // step B
        const int r = tid >> 3, n2p = tid & 7;
#pragma unroll
        for (int n1p = 0; n1p < 32; ++n1p)
            a[n1p] = z[SLOT(r, (n1p << 3) + n2p)];
        fft32_dif(a);
        float2 wb = tw[n2p << 5], wb2 = cmul(wb, wb);
        float2 be = make_float2(1.f, 0.f), bo = wb;
#pragma unroll
        for (int k1p = 0; k1p < 32; k1p += 2) {
            z[SLOT(r, (k1p << 3) + n2p)]       = (k1p == 0) ? a[0] : cmul(a[BREV5[k1p]], be);
            z[SLOT(r, ((k1p + 1) << 3) + n2p)] = cmul(a[BREV5[k1p + 1]], bo);
            be = cmul(be, wb2); bo = cmul(bo, wb2);
        }
    }
    __syncthreads();

    // step C: 8-point FFTs
#pragma unroll
    for (int u = 0; u < 4; ++u) {
        int f = tid + (u << 8);
        int k1 = f >> 5, k1p = f & 31;
        float2 b[8];
#pragma unroll
        for (int e = 0; e < 8; ++e) b[e] = z[SLOT(k1, (k1p << 3) + e)];
        fft8_dif(b);
#pragma unroll
        for (int j = 0; j < 8; ++j) z[SLOT(k1, (k1p << 3) + j)] = b[j];
    }
    __syncthreads();

    // Hermitian unpack into parity-split, conv-order layout
    const float sc = 0.5f / (float)N_FFT;   // fold in ifft 1/N
#pragma unroll
    for (int v = 0; v < 16; ++v) {
        int s = tid + (v << 8);                     // s in [0,4096)
        int k1 = s >> 8, r1 = (s >> 4) & 15, j = s & 15;
        int kp = k1 + (r1 << 4) + (BREV4[j] << 8);  // k' in [0,4096)
#pragma unroll
        for (int par = 0; par < 2; ++par) {
            int k  = 2 * kp + par;
            int km = (N_FFT - k) & (N_FFT - 1);
            float2 A = z[ZADDR(k)];
            float2 B = z[ZADDR(km)];
            float2 Bj = make_float2(B.x, -B.y);
            float2 T0 = make_float2((A.x + Bj.x) * sc, (A.y + Bj.y) * sc);
            float2 dd = csub(A, Bj);
            float2 T1 = make_float2(dd.y * sc, -dd.x * sc);
            Tc[(size_t)d0 * N_FFT + (par << 12) + s] = T0;
            Tc[(size_t)d1 * N_FFT + (par << 12) + s] = T1;
        }
    }
}

// ---------------------------------------------------------------- main conv --
// Even/odd bin split: two 4096-point chains, 32 KB LDS, 4 blocks/CU.
// Reads its own contiguous xT row into regs, writes result back over it.
__global__ __launch_bounds__(256, 4) void conv4_kernel(float2* __restrict__ xoT,
                                                       const float2* __restrict__ tw,
                                                       const float2* __restrict__ Tc) {
    __shared__ float2 z[SEQ];          // 16 rows x 256 cols, 32 KB
    const int tid = threadIdx.x;
    // XCD swizzle; consecutive sb pairs share d (T reuse in same XCD's L2)
    const int sb = (blockIdx.x & 7) * 128 + (blockIdx.x >> 3);
    const int d  = sb >> 1;
    const int pb = sb & 1;

    float2* xp = xoT + ((size_t)(pb * NCH + d) << 12);

    float2 xr[16], a[16], ie[16];
#pragma unroll
    for (int n1 = 0; n1 < 16; ++n1)
        xr[n1] = xp[(n1 << 8) + tid];            // coalesced 8B

#pragma unroll
    for (int par = 0; par < 2; ++par) {
        if (par == 1) __syncthreads();   // protect LDS reuse across chains

        // ---- stage A: regs (+modulate for odd), fft16, twiddle, -> LDS
        if (par == 0) {
#pragma unroll
            for (int n1 = 0; n1 < 16; ++n1) a[n1] = xr[n1];
        } else {
#pragma unroll
            for (int n1 = 0; n1 < 16; ++n1) {
                int n = (n1 << 8) + tid;
                a[n1] = cmul(xr[n1], tw[n]);     // coalesced tw load
            }
        }
        fft16_dif(a);
        {
            float2 w = tw[2 * tid];              // W_4096^tid
            float2 w2 = cmul(w, w);
            float2 we = make_float2(1.f, 0.f), wo = w;
#pragma unroll
            for (int k1 = 0; k1 < 16; k1 += 2) {
                z[SLOT16(k1, tid)]     = (k1 == 0) ? a[0] : cmul(a[BREV4[k1]], we);
                z[SLOT16(k1 + 1, tid)] = cmul(a[BREV4[k1 + 1]], wo);
                we = cmul(we, w2); wo = cmul(wo, w2);
            }
        }
        __syncthreads();

        // ---- stage B: FFT16 over n2 for (k1, n3)
        {
            const int k1 = tid >> 4, n3 = tid & 15;
#pragma unroll
            for (int n2 = 0; n2 < 16; ++n2)
                a[n2] = z[SLOT16(k1, (n2 << 4) + n3)];
            fft16_dif(a);
            float2 wb = tw[n3 << 5];             // W_256^{n3}
            float2 wb2 = cmul(wb, wb);
            float2 be = make_float2(1.f, 0.f), bo = wb;
#pragma unroll
            for (int r1 = 0; r1 < 16; r1 += 2) {
                z[SLOT16(k1, (r1 << 4) + n3)]       = (r1 == 0) ? a[0] : cmul(a[BREV4[r1]], be);
                z[SLOT16(k1, ((r1 + 1) << 4) + n3)] = cmul(a[BREV4[r1 + 1]], bo);
                be = cmul(be, wb2); bo = cmul(bo, wb2);
            }
        }
        __syncthreads();

        // ---- stage C fwd + pointwise + stage C inverse (fused)
        {
            const int k1 = tid >> 4, r1 = tid & 15;
#pragma unroll
            for (int n3 = 0; n3 < 16; ++n3)
                a[n3] = z[SLOT16(k1, (r1 << 4) + n3)];
            fft16_dif(a);
            const float4* tp = (const float4*)(Tc + ((size_t)d << 13) + (par << 12) + (tid << 4));
#pragma unroll
            for (int q = 0; q < 8; ++q) {
                float4 f4 = tp[q];
                a[2 * q]     = cmul(a[2 * q],     make_float2(f4.x, f4.y));
                a[2 * q + 1] = cmul(a[2 * q + 1], make_float2(f4.z, f4.w));
            }
            ifft16_dit(a);   // DIF output order == DIT input order
#pragma unroll
            for (int n3 = 0; n3 < 16; ++n3)
                z[SLOT16(k1, (r1 << 4) + n3)] = a[n3];
        }
        __syncthreads();

        // ---- stage B inverse
        {
            const int k1 = tid >> 4, n3 = tid & 15;
            float2 wb = tw[n3 << 5], wb2 = cmul(wb, wb);
            float2 be = make_float2(1.f, 0.f), bo = wb;
#pragma unroll
            for (int r1 = 0; r1 < 16; r1 += 2) {
                float2 v0 = z[SLOT16(k1, (r1 << 4) + n3)];
                float2 v1 = z[SLOT16(k1, ((r1 + 1) << 4) + n3)];
                a[BREV4[r1]]     = (r1 == 0) ? v0 : cmulj(v0, be);
                a[BREV4[r1 + 1]] = cmulj(v1, bo);
                be = cmul(be, wb2); bo = cmul(bo, wb2);
            }
            ifft16_dit(a);
#pragma unroll
            for (int n2 = 0; n2 < 16; ++n2)
                z[SLOT16(k1, (n2 << 4) + n3)] = a[n2];
        }
        __syncthreads();

        // ---- stage A inverse (thread-private column slots)
        {
            float2 w = tw[2 * tid], w2 = cmul(w, w);
            float2 we = make_float2(1.f, 0.f), wo = w;
#pragma unroll
            for (int k1 = 0; k1 < 16; k1 += 2) {
                float2 v0 = z[SLOT16(k1, tid)];
                float2 v1 = z[SLOT16(k1 + 1, tid)];
                a[BREV4[k1]]     = (k1 == 0) ? v0 : cmulj(v0, we);
                a[BREV4[k1 + 1]] = cmulj(v1, wo);
                we = cmul(we, w2); wo = cmul(wo, w2);
            }
            ifft16_dit(a);   // a[n1] = U_par[n1*256 + tid]
        }

        if (par == 0) {
#pragma unroll
            for (int n1 = 0; n1 < 16; ++n1) ie[n1] = a[n1];
        } else {
#pragma unroll
            for (int n1 = 0; n1 < 16; ++n1) {
                int n = (n1 << 8) + tid;
                xp[n] = cadd(ie[n1], cmulj(a[n1], tw[n]));   // coalesced 8B
            }
        }
    }
}

// ---------------------------------------------------------------- transpose --
// oT[pb][d][n] (float2: {b=2pb, b=2pb+1}) -> out[b][n][d]. LDS-tiled 32d x 64n.
__global__ __launch_bounds__(256) void transpose_out(const float2* __restrict__ oT,
                                                     float* __restrict__ out) {
    __shared__ float2 tile[32][65];
    const int tid = threadIdx.x;
    const int bid = blockIdx.x;
    const int pb = bid >> 10;
    const int dt = (bid >> 6) & 15;
    const int nt = bid & 63;
    const int d0 = dt << 5, n0 = nt << 6;

    {
        const int nl = tid & 63, dl = tid >> 6;
#pragma unroll
        for (int i = 0; i < 8; ++i) {
            int dd = dl + (i << 2);
            tile[dd][nl] = oT[(((size_t)(pb * NCH + d0 + dd)) << 12) + n0 + nl];
        }
    }
    __syncthreads();
    {
        const int dl = tid & 31, ns = tid >> 5;
        float* o0 = out + (size_t)(2 * pb) * SEQ * NCH;
        float* o1 = o0 + (size_t)SEQ * NCH;
#pragma unroll
        for (int j = 0; j < 8; ++j) {
            int nn = n0 + ns + (j << 3);
            float2 v = tile[dl][ns + (j << 3)];
            o0[(size_t)nn * NCH + d0 + dl] = v.x;
            o1[(size_t)nn * NCH + d0 + dl] = v.y;
        }
    }
}

// =================== fallback path (small ws): round-5 kernels ==============
__global__ __launch_bounds__(256) void tfft2_kernel(const float* __restrict__ t,
                                                    const float2* __restrict__ tw,
                                                    float2* __restrict__ Tc) {
    __shared__ float2 z[N_FFT];
    const int tid = threadIdx.x;
    const int d0 = blockIdx.x * 2;
    const int d1 = d0 + 1;

    float2 a[32];
#pragma unroll
    for (int n1 = 0; n1 < 32; ++n1) {
        int n = (n1 << 8) + tid;
        float va = 0.f, vb = 0.f;
        if (n < TLEN) {
            va = t[(size_t)n * NCH + d0];
            vb = t[(size_t)n * NCH + d1];
        }
        a[n1] = make_float2(va, vb);
    }
    fft32_dif(a);
    {
        float2 w = tw[tid], w2 = cmul(w, w);
        float2 we = make_float2(1.f, 0.f), wo = w;
#pragma unroll
        for (int k1 = 0; k1 < 32; k1 += 2) {
            z[SLOT(k1, tid)]     = (k1 == 0) ? a[0] : cmul(a[BREV5[k1]], we);
            z[SLOT(k1 + 1, tid)] = cmul(a[BREV5[k1 + 1]], wo);
            we = cmul(we, w2); wo = cmul(wo, w2);
        }
    }
    __syncthreads();
    {
        const int r = tid >> 3, n2p = tid & 7;
#pragma unroll
        for (int n1p = 0; n1p < 32; ++n1p)
            a[n1p] = z[SLOT(r, (n1p << 3) + n2p)];
        fft32_dif(a);
        float2 wb = tw[n2p << 5], wb2 = cmul(wb, wb);
        float2 be = make_float2(1.f, 0.f), bo = wb;
#pragma unroll
        for (int k1p = 0; k1p < 32; k1p += 2) {
            z[SLOT(r, (k1p << 3) + n2p)]       = (k1p == 0) ? a[0] : cmul(a[BREV5[k1p]], be);
            z[SLOT(r, ((k1p + 1) << 3) + n2p)] = cmul(a[BREV5[k1p + 1]], bo);
            be = cmul(be, wb2); bo = cmul(bo, wb2);
        }
    }
    __syncthreads();
#pragma unroll
    for (int u = 0; u < 4; ++u) {
        int f = tid + (u << 8);
        int k1 = f >> 5, k1p = f & 31;
        float2 b[8];
#pragma unroll
        for (int e = 0; e < 8; ++e) b[e] = z[SLOT(k1, (k1p << 3) + e)];
        fft8_dif(b);
#pragma unroll
        for (int j = 0; j < 8; ++j) z[SLOT(k1, (k1p << 3) + j)] = b[j];
    }
    __syncthreads();

    const float sc = 0.5f / (float)N_FFT;
#pragma unroll
    for (int v = 0; v < 16; ++v) {
        int s = tid + (v << 8);
        int k1 = s >> 8, r1 = (s >> 4) & 15, j = s & 15;
        int kp = k1 + (r1 << 4) + (BREV4[j] << 8);
#pragma unroll
        for (int par = 0; par < 2; ++par) {
            int k  = 2 * kp + par;
            int km = (N_FFT - k) & (N_FFT - 1);
            float2 A = z[ZADDR(k)];
            float2 B = z[ZADDR(km)];
            float2 Bj = make_float2(B.x, -B.y);
            float2 T0 = make_float2((A.x + Bj.x) * sc, (A.y + Bj.y) * sc);
            float2 dd = csub(A, Bj);
            float2 T1 = make_float2(dd.y * sc, -dd.x * sc);
            Tc[(size_t)d0 * N_FFT + (par << 12) + s] = T0;
            Tc[(size_t)d1 * N_FFT + (par << 12) + s] = T1;
        }
    }
}

template<bool OT>
__global__ __launch_bounds__(256, 4) void conv3_kernel(const float* __restrict__ x,
                                                       const float2* __restrict__ tw,
                                                       const float2* __restrict__ Tc,
                                                       float2* __restrict__ oT,
                                                       float* __restrict__ out) {
    __shared__ float2 z[SEQ];
    const int tid = threadIdx.x;
    const int sb = (blockIdx.x & 7) * 128 + (blockIdx.x >> 3);
    const int d  = sb >> 1;
    const int pb = sb & 1;

    const float* x0 = x + (size_t)(2 * pb) * SEQ * NCH + d;
    const float* x1 = x0 + (size_t)SEQ * NCH;

    float2 xr[16], a[16], ie[16];
#pragma unroll
    for (int n1 = 0; n1 < 16; ++n1) {
        int n = (n1 << 8) + tid;
        xr[n1] = make_float2(x0[(size_t)n * NCH], x1[(size_t)n * NCH]);
    }

#pragma unroll
    for (int par = 0; par < 2; ++par) {
        if (par == 1) __syncthreads();

        if (par == 0) {
#pragma unroll
            for (int n1 = 0; n1 < 16; ++n1) a[n1] = xr[n1];
        } else {
#pragma unroll
            for (int n1 = 0; n1 < 16; ++n1) {
                int n = (n1 << 8) + tid;
                a[n1] = cmul(xr[n1], tw[n]);
            }
        }
        fft16_dif(a);
        {
            float2 w = tw[2 * tid], w2 = cmul(w, w);
            float2 we = make_float2(1.f, 0.f), wo = w;
#pragma unroll
            for (int k1 = 0; k1 < 16; k1 += 2) {
                z[SLOT16(k1, tid)]     = (k1 == 0) ? a[0] : cmul(a[BREV4[k1]], we);
                z[SLOT16(k1 + 1, tid)] = cmul(a[BREV4[k1 + 1]], wo);
                we = cmul(we, w2); wo = cmul(wo, w2);
            }
        }
        __syncthreads();
        {
            const int k1 = tid >> 4, n3 = tid & 15;
#pragma unroll
            for (int n2 = 0; n2 < 16; ++n2)
                a[n2] = z[SLOT16(k1, (n2 << 4) + n3)];
            fft16_dif(a);
            float2 wb = tw[n3 << 5], wb2 = cmul(wb, wb);
            float2 be = make_float2(1.f, 0.f), bo = wb;
#pragma unroll
            for (int r1 = 0; r1 < 16; r1 += 2) {
                z[SLOT16(k1, (r1 << 4) + n3)]       = (r1 == 0) ? a[0] : cmul(a[BREV4[r1]], be);
                z[SLOT16(k1, ((r1 + 1) << 4) + n3)] = cmul(a[BREV4[r1 + 1]], bo);
                be = cmul(be, wb2); bo = cmul(bo, wb2);
            }
        }
        __syncthreads();
        {
            const int k1 = tid >> 4, r1 = tid & 15;
#pragma unroll
            for (int n3 = 0; n3 < 16; ++n3)
                a[n3] = z[SLOT16(k1, (r1 << 4) + n3)];
            fft16_dif(a);
            const float4* tp = (const float4*)(Tc + ((size_t)d << 13) + (par << 12) + (tid << 4));
#pragma unroll
            for (int q = 0; q < 8; ++q) {
                float4 f4 = tp[q];
                a[2 * q]     = cmul(a[2 * q],     make_float2(f4.x, f4.y));
                a[2 * q + 1] = cmul(a[2 * q + 1], make_float2(f4.z, f4.w));
            }
            ifft16_dit(a);
#pragma unroll
            for (int n3 = 0; n3 < 16; ++n3)
                z[SLOT16(k1, (r1 << 4) + n3)] = a[n3];
        }
        __syncthreads();
        {
            const int k1 = tid >> 4, n3 = tid & 15;
            float2 wb = tw[n3 << 5], wb2 = cmul(wb, wb);
            float2 be = make_float2(1.f, 0.f), bo = wb;
#pragma unroll
            for (int r1 = 0; r1 < 16; r1 += 2) {
                float2 v0 = z[SLOT16(k1, (r1 << 4) + n3)];
                float2 v1 = z[SLOT16(k1, ((r1 + 1) << 4) + n3)];
                a[BREV4[r1]]     = (r1 == 0) ? v0 : cmulj(v0, be);
                a[BREV4[r1 + 1]] = cmulj(v1, bo);
                be = cmul(be, wb2); bo = cmul(bo, wb2);
            }
            ifft16_dit(a);
#pragma unroll
            for (int n2 = 0; n2 < 16; ++n2)
                z[SLOT16(k1, (n2 << 4) + n3)] = a[n2];
        }
        __syncthreads();
        {
            float2 w = tw[2 * tid], w2 = cmul(w, w);
            float2 we = make_float2(1.f, 0.f), wo = w;
#pragma unroll
            for (int k1 = 0; k1 < 16; k1 += 2) {
                float2 v0 = z[SLOT16(k1, tid)];
                float2 v1 = z[SLOT16(k1 + 1, tid)];
                a[BREV4[k1]]     = (k1 == 0) ? v0 : cmulj(v0, we);
                a[BREV4[k1 + 1]] = cmulj(v1, wo);
                we = cmul(we, w2); wo = cmul(wo, w2);
            }
            ifft16_dit(a);
        }

        if (par == 0) {
#pragma unroll
            for (int n1 = 0; n1 < 16; ++n1) ie[n1] = a[n1];
        } else {
            if constexpr (OT) {
                float2* op = oT + (((size_t)(pb * NCH + d)) << 12);
#pragma unroll
                for (int n1 = 0; n1 < 16; ++n1) {
                    int n = (n1 << 8) + tid;
                    op[n] = cadd(ie[n1], cmulj(a[n1], tw[n]));
                }
            } else {
                float* o0 = out + (size_t)(2 * pb) * SEQ * NCH + d;
                float* o1 = o0 + (size_t)SEQ * NCH;
#pragma unroll
                for (int n1 = 0; n1 < 16; ++n1) {
                    int n = (n1 << 8) + tid;
                    float2 o = cadd(ie[n1], cmulj(a[n1], tw[n]));
                    o0[(size_t)n * NCH] = o.x;
                    o1[(size_t)n * NCH] = o.y;
                }
            }
        }
    }
}

extern "C" void kernel_launch(void* const* d_in, const int* in_sizes, int n_in,
                              void* d_out, int out_size, void* d_ws, size_t ws_size,
                              hipStream_t stream) {
    (void)in_sizes; (void)n_in; (void)out_size;
    const float* x = (const float*)d_in[0];
    const float* t = (const float*)d_in[1];
    float* out = (float*)d_out;

    float2* tw  = (float2*)d_ws;                   // 8192 f2 = 64 KB
    float2* Tc  = tw + N_FFT;                      // 512*8192 f2 = 33.55 MB
    float2* xoT = Tc + (size_t)NCH * N_FFT;        // 2*512*4096 f2 = 33.55 MB
    float2* tT  = xoT + 2ull * NCH * SEQ;          // 256*8192 f2 = 16.78 MB

    const size_t need_full = sizeof(float2) * ((size_t)N_FFT + (size_t)NCH * N_FFT
                                               + 2ull * NCH * SEQ
                                               + 256ull * N_FFT);   // ~84 MB
    const size_t need_ot   = sizeof(float2) * ((size_t)N_FFT + (size_t)NCH * N_FFT
                                               + 2ull * NCH * SEQ); // ~67.2 MB

    twiddle_init<<<N_FFT / 256, 256, 0, stream>>>(tw);
    if (ws_size >= need_full) {
        transpose_x<<<1024, 256, 0, stream>>>(x, xoT);
        transpose_t<<<512, 256, 0, stream>>>(t, tT);
        tfft3_kernel<<<NCH / 2, 256, 0, stream>>>(tT, tw, Tc);
        conv4_kernel<<<1024, 256, 0, stream>>>(xoT, tw, Tc);
        transpose_out<<<2048, 256, 0, stream>>>(xoT, out);
    } else if (ws_size >= need_ot) {
        tfft2_kernel<<<NCH / 2, 256, 0, stream>>>(t, tw, Tc);
        conv3_kernel<true><<<1024, 256, 0, stream>>>(x, tw, Tc, xoT, out);
        transpose_out<<<2048, 256, 0, stream>>>(xoT, out);
    } else {
        tfft2_kernel<<<NCH / 2, 256, 0, stream>>>(t, tw, Tc);
        conv3_kernel<false><<<1024, 256, 0, stream>>>(x, tw, Tc, nullptr, out);
    }
}

// Round 7
// 124.003 us; speedup vs baseline: 1.4629x; 1.0872x over previous
//
#include <hip/hip_runtime.h>
#include <math.h>

// Problem constants (b=4, n=m=l=4096, d=512, fft_len=8192, t_len=2l-2=8190)
#define N_FFT   8192
#define SEQ     4096
#define NCH     512
#define TLEN    8190

__device__ __forceinline__ float2 cmul(float2 a, float2 b) {
    return make_float2(a.x * b.x - a.y * b.y, a.x * b.y + a.y * b.x);
}
__device__ __forceinline__ float2 cmulj(float2 a, float2 b) {   // a * conj(b)
    return make_float2(a.x * b.x + a.y * b.y, a.y * b.x - a.x * b.y);
}
__device__ __forceinline__ float2 cadd(float2 a, float2 b) {
    return make_float2(a.x + b.x, a.y + b.y);
}
__device__ __forceinline__ float2 csub(float2 a, float2 b) {
    return make_float2(a.x - b.x, a.y - b.y);
}

// W32^j = exp(-2*pi*i*j/32), j in [0,16)
constexpr float W32C[16] = {
    1.0f, 0.9807852804032304f, 0.9238795325112867f, 0.8314696123025452f,
    0.7071067811865476f, 0.5555702330196023f, 0.3826834323650898f, 0.1950903220161283f,
    0.0f, -0.1950903220161282f, -0.3826834323650897f, -0.5555702330196020f,
    -0.7071067811865475f, -0.8314696123025453f, -0.9238795325112867f, -0.9807852804032304f
};
constexpr float W32S[16] = {
    -0.0f, -0.1950903220161283f, -0.3826834323650898f, -0.5555702330196022f,
    -0.7071067811865476f, -0.8314696123025452f, -0.9238795325112867f, -0.9807852804032304f,
    -1.0f, -0.9807852804032304f, -0.9238795325112867f, -0.8314696123025453f,
    -0.7071067811865476f, -0.5555702330196022f, -0.3826834323650899f, -0.1950903220161286f
};

constexpr int BREV5[32] = {0,16,8,24,4,20,12,28,2,18,10,26,6,22,14,30,
                           1,17,9,25,5,21,13,29,3,19,11,27,7,23,15,31};
constexpr int BREV4[16] = {0,8,4,12,2,10,6,14,1,9,5,13,3,11,7,15};

__device__ __forceinline__ int brev3i(int b) {
    return ((b & 1) << 2) | (b & 2) | ((b & 4) >> 2);
}

// ---------------------------------------------------------------- reg FFTs ---
__device__ __forceinline__ void fft32_dif(float2 a[32]) {
#pragma unroll
    for (int s = 4; s >= 0; --s) {
        const int h = 1 << s;
#pragma unroll
        for (int g = 0; g < 32; g += 2 * h) {
#pragma unroll
            for (int i = 0; i < h; ++i) {
                float2 x0 = a[g + i], x1 = a[g + i + h];
                a[g + i] = cadd(x0, x1);
                float2 w = make_float2(W32C[i << (4 - s)], W32S[i << (4 - s)]);
                a[g + i + h] = cmul(csub(x0, x1), w);
            }
        }
    }
}

__device__ __forceinline__ void fft16_dif(float2 a[16]) {
#pragma unroll
    for (int s = 3; s >= 0; --s) {
        const int h = 1 << s;
#pragma unroll
        for (int g = 0; g < 16; g += 2 * h) {
#pragma unroll
            for (int i = 0; i < h; ++i) {
                float2 x0 = a[g + i], x1 = a[g + i + h];
                a[g + i] = cadd(x0, x1);
                float2 w = make_float2(W32C[i << (4 - s)], W32S[i << (4 - s)]);
                a[g + i + h] = cmul(csub(x0, x1), w);
            }
        }
    }
}

__device__ __forceinline__ void ifft16_dit(float2 a[16]) {
#pragma unroll
    for (int s = 0; s <= 3; ++s) {
        const int h = 1 << s;
#pragma unroll
        for (int g = 0; g < 16; g += 2 * h) {
#pragma unroll
            for (int i = 0; i < h; ++i) {
                float2 w = make_float2(W32C[i << (4 - s)], -W32S[i << (4 - s)]);
                float2 t = cmul(a[g + i + h], w);
                float2 x0 = a[g + i];
                a[g + i] = cadd(x0, t);
                a[g + i + h] = csub(x0, t);
            }
        }
    }
}

__device__ __forceinline__ void fft8_dif(float2 a[8]) {
#pragma unroll
    for (int s = 2; s >= 0; --s) {
        const int h = 1 << s;
#pragma unroll
        for (int g = 0; g < 8; g += 2 * h) {
#pragma unroll
            for (int i = 0; i < h; ++i) {
                float2 x0 = a[g + i], x1 = a[g + i + h];
                a[g + i] = cadd(x0, x1);
                int e = (i << (2 - s)) << 2;   // W8^m = W32^{4m}
                float2 w = make_float2(W32C[e], W32S[e]);
                a[g + i + h] = cmul(csub(x0, x1), w);
            }
        }
    }
}

// bank-conflict-reduced LDS slot, 32-row layout (tfft)
__device__ __forceinline__ int SLOT(int r, int c) {
    return (r << 8) + (c ^ ((c >> 4) & 7) ^ ((r & 1) << 3));
}
// LDS slot of frequency bin q after tfft forward stage C
__device__ __forceinline__ int ZADDR(int q) {
    return SLOT(q & 31, (((q >> 5) & 31) << 3) + brev3i((q >> 10) & 7));
}
// 16-row layout (conv)
__device__ __forceinline__ int SLOT16(int r, int c) {
    return (r << 8) + (c ^ ((c >> 4) & 7) ^ ((r & 1) << 3));
}

// ---------------------------------------------------------------- twiddles ---
__global__ __launch_bounds__(256) void twiddle_init(float2* __restrict__ tw) {
    int k = blockIdx.x * 256 + threadIdx.x;
    double th = -2.0 * 3.14159265358979323846 * (double)k / (double)N_FFT;
    tw[k] = make_float2((float)cos(th), (float)sin(th));
}

// ---------------------------------------------------------------- transposes -
// Fused input transposes.
// bid < 1024:  x[b][n][d] -> xT[pb][d][n]  (64n x 64d tiles)
// bid >= 1024: t[n][d] -> tT[dp][n] (zero-padded to 8192)
__global__ __launch_bounds__(256) void transpose_in(const float* __restrict__ x,
                                                    const float* __restrict__ t,
                                                    float2* __restrict__ xT,
                                                    float2* __restrict__ tT) {
    __shared__ float tX[64][65], tY[64][65];
    const int tid = threadIdx.x;
    if (blockIdx.x < 1024) {
        const int bid = blockIdx.x;        // [pb:2][dt:8][nt:64]
        const int pb = bid >> 9;
        const int dt = (bid >> 6) & 7;
        const int nt = bid & 63;
        const int d0 = dt << 6, n0 = nt << 6;
        const float* x0 = x + (size_t)(2 * pb) * SEQ * NCH;
        const float* x1 = x0 + (size_t)SEQ * NCH;
        {
            const int c = tid & 63, r4 = tid >> 6;
#pragma unroll
            for (int it = 0; it < 16; ++it) {
                int row = r4 + (it << 2);
                size_t off = (size_t)(n0 + row) * NCH + d0 + c;
                tX[row][c] = x0[off];
                tY[row][c] = x1[off];
            }
        }
        __syncthreads();
        {
            const int nc = tid & 63, dr4 = tid >> 6;
#pragma unroll
            for (int it = 0; it < 16; ++it) {
                int dr = dr4 + (it << 2);
                xT[(((size_t)(pb * NCH + d0 + dr)) << 12) + n0 + nc] =
                    make_float2(tX[nc][dr], tY[nc][dr]);
            }
        }
    } else {
        const int bid = blockIdx.x - 1024; // [nt:128][dpt:4]
        const int nt = bid >> 2, dpt = bid & 3;
        const int n0 = nt << 6, dp0 = dpt << 6;
        {
            const int c = tid & 63, r4 = tid >> 6;
#pragma unroll
            for (int it = 0; it < 16; ++it) {
                int row = r4 + (it << 2);
                int nn = n0 + row;
                float2 v = make_float2(0.f, 0.f);
                if (nn < TLEN)
                    v = *(const float2*)(t + (size_t)nn * NCH + ((dp0 + c) << 1));
                tX[row][c] = v.x;
                tY[row][c] = v.y;
            }
        }
        __syncthreads();
        {
            const int nc = tid & 63, dr4 = tid >> 6;
#pragma unroll
            for (int it = 0; it < 16; ++it) {
                int dr = dr4 + (it << 2);
                tT[(((size_t)(dp0 + dr)) << 13) + n0 + nc] =
                    make_float2(tX[nc][dr], tY[nc][dr]);
            }
        }
    }
}

// ---------------------------------------------------------------- t spectra --
// Monolithic 8192 FFT (32x32x8), channels d0=2*bid, d1=2*bid+1 packed, input
// from tT (coalesced). Emits parity-split spectrum in conv stage-C order,
// prescaled by 1/8192.
__global__ __launch_bounds__(256) void tfft3_kernel(const float2* __restrict__ tT,
                                                    const float2* __restrict__ tw,
                                                    float2* __restrict__ Tc) {
    __shared__ float2 z[N_FFT];
    const int tid = threadIdx.x;
    const int d0 = blockIdx.x * 2;
    const int d1 = d0 + 1;
    const float2* tp = tT + ((size_t)blockIdx.x << 13);

    float2 a[32];
#pragma unroll
    for (int n1 = 0; n1 < 32; ++n1)
        a[n1] = tp[(n1 << 8) + tid];
    fft32_dif(a);
    {   // twiddle w^k1, w = tw[tid]; even/odd incremental chains
        float2 w = tw[tid], w2 = cmul(w, w);
        float2 we = make_float2(1.f, 0.f), wo = w;
#pragma unroll
        for (int k1 = 0; k1 < 32; k1 += 2) {
            z[SLOT(k1, tid)]     = (k1 == 0) ? a[0] : cmul(a[BREV5[k1]], we);
            z[SLOT(k1 + 1, tid)] = cmul(a[BREV5[k1 + 1]], wo);
            we = cmul(we, w2); wo = cmul(wo, w2);
        }
    }
    __syncthreads();

    {   // step B
        const int r = tid >> 3, n2p = tid & 7;
#pragma unroll
        for (int n1p = 0; n1p < 32; ++n1p)
            a[n1p] = z[SLOT(r, (n1p << 3) + n2p)];
        fft32_dif(a);
        float2 wb = tw[n2p << 5], wb2 = cmul(wb, wb);
        float2 be = make_float2(1.f, 0.f), bo = wb;
#pragma unroll
        for (int k1p = 0; k1p < 32; k1p += 2) {
            z[SLOT(r, (k1p << 3) + n2p)]       = (k1p == 0) ? a[0] : cmul(a[BREV5[k1p]], be);
            z[SLOT(r, ((k1p + 1) << 3) + n2p)] = cmul(a[BREV5[k1p + 1]], bo);
            be = cmul(be, wb2); bo = cmul(bo, wb2);
        }
    }
    __syncthreads();

    // step C: 8-point FFTs
#pragma unroll
    for (int u = 0; u < 4; ++u) {
        int f = tid + (u << 8);
        int k1 = f >> 5, k1p = f & 31;
        float2 b[8];
#pragma unroll
        for (int e = 0; e < 8; ++e) b[e] = z[SLOT(k1, (k1p << 3) + e)];
        fft8_dif(b);
#pragma unroll
        for (int j = 0; j < 8; ++j) z[SLOT(k1, (k1p << 3) + j)] = b[j];
    }
    __syncthreads();

    // Hermitian unpack into parity-split, conv-order layout
    const float sc = 0.5f / (float)N_FFT;   // fold in ifft 1/N
#pragma unroll
    for (int v = 0; v < 16; ++v) {
        int s = tid + (v << 8);                     // s in [0,4096)
        int k1 = s >> 8, r1 = (s >> 4) & 15, j = s & 15;
        int kp = k1 + (r1 << 4) + (BREV4[j] << 8);  // k' in [0,4096)
#pragma unroll
        for (int par = 0; par < 2; ++par) {
            int k  = 2 * kp + par;
            int km = (N_FFT - k) & (N_FFT - 1);
            float2 A = z[ZADDR(k)];
            float2 B = z[ZADDR(km)];
            float2 Bj = make_float2(B.x, -B.y);
            float2 T0 = make_float2((A.x + Bj.x) * sc, (A.y + Bj.y) * sc);
            float2 dd = csub(A, Bj);
            float2 T1 = make_float2(dd.y * sc, -dd.x * sc);
            Tc[(size_t)d0 * N_FFT + (par << 12) + s] = T0;
            Tc[(size_t)d1 * N_FFT + (par << 12) + s] = T1;
        }
    }
}

// ---------------------------------------------------------------- main conv --
// One 512-thread block per channel d. Lower 256 threads: even-bin chain;
// upper 256: odd-bin chain — simultaneously, in two 32 KB LDS halves.
// Batch pairs pb=0,1 sequential, pb=1 x-row prefetched into regs.
// Recombine o[n] = U_e[n] + conj(w[n])*U_o[n] via linear LDS exchange.
__global__ __launch_bounds__(512, 4) void conv5_kernel(float2* __restrict__ xoT,
                                                       const float2* __restrict__ tw,
                                                       const float2* __restrict__ Tc) {
    __shared__ float2 z[2 * SEQ];      // 64 KB: [par][16 rows][256 cols]
    const int tid = threadIdx.x;
    const int par = tid >> 8;          // chain parity (thread half)
    const int t   = tid & 255;         // local lane within chain
    const int d   = blockIdx.x;
    float2* zb = z + (par << 12);

    float2 xr[16], a[16];
    {   // load pb=0 row (both halves read the same row; upper hits L1/L2)
        const float2* xp0 = xoT + ((size_t)d << 12);
#pragma unroll
        for (int n1 = 0; n1 < 16; ++n1)
            xr[n1] = xp0[(n1 << 8) + t];
    }

#pragma unroll
    for (int pb = 0; pb < 2; ++pb) {
        if (pb == 1) __syncthreads();    // combine-reads done before reuse

        // ---- stage A: regs (+modulate for odd chain), fft16, twiddle, -> LDS
        if (par == 0) {
#pragma unroll
            for (int n1 = 0; n1 < 16; ++n1) a[n1] = xr[n1];
        } else {
#pragma unroll
            for (int n1 = 0; n1 < 16; ++n1)
                a[n1] = cmul(xr[n1], tw[(n1 << 8) + t]);
        }
        fft16_dif(a);
        {
            float2 w = tw[2 * t];        // W_4096^t
            float2 w2 = cmul(w, w);
            float2 we = make_float2(1.f, 0.f), wo = w;
#pragma unroll
            for (int k1 = 0; k1 < 16; k1 += 2) {
                zb[SLOT16(k1, t)]     = (k1 == 0) ? a[0] : cmul(a[BREV4[k1]], we);
                zb[SLOT16(k1 + 1, t)] = cmul(a[BREV4[k1 + 1]], wo);
                we = cmul(we, w2); wo = cmul(wo, w2);
            }
        }
        if (pb == 0) {                   // prefetch pb=1 row (hidden under LDS phases)
            const float2* xp1 = xoT + ((size_t)(NCH + d) << 12);
#pragma unroll
            for (int n1 = 0; n1 < 16; ++n1)
                xr[n1] = xp1[(n1 << 8) + t];
        }
        __syncthreads();

        // ---- stage B
        {
            const int k1 = t >> 4, n3 = t & 15;
#pragma unroll
            for (int n2 = 0; n2 < 16; ++n2)
                a[n2] = zb[SLOT16(k1, (n2 << 4) + n3)];
            fft16_dif(a);
            float2 wb = tw[n3 << 5];     // W_256^{n3}
            float2 wb2 = cmul(wb, wb);
            float2 be = make_float2(1.f, 0.f), bo = wb;
#pragma unroll
            for (int r1 = 0; r1 < 16; r1 += 2) {
                zb[SLOT16(k1, (r1 << 4) + n3)]       = (r1 == 0) ? a[0] : cmul(a[BREV4[r1]], be);
                zb[SLOT16(k1, ((r1 + 1) << 4) + n3)] = cmul(a[BREV4[r1 + 1]], bo);
                be = cmul(be, wb2); bo = cmul(bo, wb2);
            }
        }
        __syncthreads();

        // ---- stage C fwd + pointwise (own parity plane) + stage C inverse
        {
            const int k1 = t >> 4, r1 = t & 15;
#pragma unroll
            for (int n3 = 0; n3 < 16; ++n3)
                a[n3] = zb[SLOT16(k1, (r1 << 4) + n3)];
            fft16_dif(a);
            const float4* tp = (const float4*)(Tc + ((size_t)d << 13) + (par << 12) + (t << 4));
#pragma unroll
            for (int q = 0; q < 8; ++q) {
                float4 f4 = tp[q];
                a[2 * q]     = cmul(a[2 * q],     make_float2(f4.x, f4.y));
                a[2 * q + 1] = cmul(a[2 * q + 1], make_float2(f4.z, f4.w));
            }
            ifft16_dit(a);               // DIF output order == DIT input order
#pragma unroll
            for (int n3 = 0; n3 < 16; ++n3)
                zb[SLOT16(k1, (r1 << 4) + n3)] = a[n3];
        }
        __syncthreads();

        // ---- stage B inverse
        {
            const int k1 = t >> 4, n3 = t & 15;
            float2 wb = tw[n3 << 5], wb2 = cmul(wb, wb);
            float2 be = make_float2(1.f, 0.f), bo = wb;
#pragma unroll
            for (int r1 = 0; r1 < 16; r1 += 2) {
                float2 v0 = zb[SLOT16(k1, (r1 << 4) + n3)];
                float2 v1 = zb[SLOT16(k1, ((r1 + 1) << 4) + n3)];
                a[BREV4[r1]]     = (r1 == 0) ? v0 : cmulj(v0, be);
                a[BREV4[r1 + 1]] = cmulj(v1, bo);
                be = cmul(be, wb2); bo = cmul(bo, wb2);
            }
            ifft16_dit(a);
#pragma unroll
            for (int n2 = 0; n2 < 16; ++n2)
                zb[SLOT16(k1, (n2 << 4) + n3)] = a[n2];
        }
        __syncthreads();

        // ---- stage A inverse (thread-private column slots)
        {
            float2 w = tw[2 * t], w2 = cmul(w, w);
            float2 we = make_float2(1.f, 0.f), wo = w;
#pragma unroll
            for (int k1 = 0; k1 < 16; k1 += 2) {
                float2 v0 = zb[SLOT16(k1, t)];
                float2 v1 = zb[SLOT16(k1 + 1, t)];
                a[BREV4[k1]]     = (k1 == 0) ? v0 : cmulj(v0, we);
                a[BREV4[k1 + 1]] = cmulj(v1, wo);
                we = cmul(we, w2); wo = cmul(wo, w2);
            }
            ifft16_dit(a);               // a[n1] = U_par[n1*256 + t]
        }
        __syncthreads();                 // all A-inv reads done before overwrite

        // ---- write U linear, exchange, combine, store
        {
#pragma unroll
            for (int n1 = 0; n1 < 16; ++n1)
                zb[(n1 << 8) + t] = a[n1];
        }
        __syncthreads();
        {
            float2* xp = xoT + ((size_t)(pb * NCH + d) << 12);
#pragma unroll
            for (int j = 0; j < 8; ++j) {
                int n = (j << 9) + tid;          // all 512 threads, coalesced
                float2 ue = z[n];
                float2 uo = z[SEQ + n];
                xp[n] = cadd(ue, cmulj(uo, tw[n]));
            }
        }
    }
}

// ---------------------------------------------------------------- transpose --
// oT[pb][d][n] (float2: {b=2pb, b=2pb+1}) -> out[b][n][d]. LDS-tiled 32d x 64n.
__global__ __launch_bounds__(256) void transpose_out(const float2* __restrict__ oT,
                                                     float* __restrict__ out) {
    __shared__ float2 tile[32][65];
    const int tid = threadIdx.x;
    const int bid = blockIdx.x;
    const int pb = bid >> 10;
    const int dt = (bid >> 6) & 15;
    const int nt = bid & 63;
    const int d0 = dt << 5, n0 = nt << 6;

    {
        const int nl = tid & 63, dl = tid >> 6;
#pragma unroll
        for (int i = 0; i < 8; ++i) {
            int dd = dl + (i << 2);
            tile[dd][nl] = oT[(((size_t)(pb * NCH + d0 + dd)) << 12) + n0 + nl];
        }
    }
    __syncthreads();
    {
        const int dl = tid & 31, ns = tid >> 5;
        float* o0 = out + (size_t)(2 * pb) * SEQ * NCH;
        float* o1 = o0 + (size_t)SEQ * NCH;
#pragma unroll
        for (int j = 0; j < 8; ++j) {
            int nn = n0 + ns + (j << 3);
            float2 v = tile[dl][ns + (j << 3)];
            o0[(size_t)nn * NCH + d0 + dl] = v.x;
            o1[(size_t)nn * NCH + d0 + dl] = v.y;
        }
    }
}

// =================== fallback path (small ws) ===============================
__global__ __launch_bounds__(256) void tfft2_kernel(const float* __restrict__ t,
                                                    const float2* __restrict__ tw,
                                                    float2* __restrict__ Tc) {
    __shared__ float2 z[N_FFT];
    const int tid = threadIdx.x;
    const int d0 = blockIdx.x * 2;
    const int d1 = d0 + 1;

    float2 a[32];
#pragma unroll
    for (int n1 = 0; n1 < 32; ++n1) {
        int n = (n1 << 8) + tid;
        float va = 0.f, vb = 0.f;
        if (n < TLEN) {
            va = t[(size_t)n * NCH + d0];
            vb = t[(size_t)n * NCH + d1];
        }
        a[n1] = make_float2(va, vb);
    }
    fft32_dif(a);
    {
        float2 w = tw[tid], w2 = cmul(w, w);
        float2 we = make_float2(1.f, 0.f), wo = w;
#pragma unroll
        for (int k1 = 0; k1 < 32; k1 += 2) {
            z[SLOT(k1, tid)]     = (k1 == 0) ? a[0] : cmul(a[BREV5[k1]], we);
            z[SLOT(k1 + 1, tid)] = cmul(a[BREV5[k1 + 1]], wo);
            we = cmul(we, w2); wo = cmul(wo, w2);
        }
    }
    __syncthreads();
    {
        const int r = tid >> 3, n2p = tid & 7;
#pragma unroll
        for (int n1p = 0; n1p < 32; ++n1p)
            a[n1p] = z[SLOT(r, (n1p << 3) + n2p)];
        fft32_dif(a);
        float2 wb = tw[n2p << 5], wb2 = cmul(wb, wb);
        float2 be = make_float2(1.f, 0.f), bo = wb;
#pragma unroll
        for (int k1p = 0; k1p < 32; k1p += 2) {
            z[SLOT(r, (k1p << 3) + n2p)]       = (k1p == 0) ? a[0] : cmul(a[BREV5[k1p]], be);
            z[SLOT(r, ((k1p + 1) << 3) + n2p)] = cmul(a[BREV5[k1p + 1]], bo);
            be = cmul(be, wb2); bo = cmul(bo, wb2);
        }
    }
    __syncthreads();
#pragma unroll
    for (int u = 0; u < 4; ++u) {
        int f = tid + (u << 8);
        int k1 = f >> 5, k1p = f & 31;
        float2 b[8];
#pragma unroll
        for (int e = 0; e < 8; ++e) b[e] = z[SLOT(k1, (k1p << 3) + e)];
        fft8_dif(b);
#pragma unroll
        for (int j = 0; j < 8; ++j) z[SLOT(k1, (k1p << 3) + j)] = b[j];
    }
    __syncthreads();

    const float sc = 0.5f / (float)N_FFT;
#pragma unroll
    for (int v = 0; v < 16; ++v) {
        int s = tid + (v << 8);
        int k1 = s >> 8, r1 = (s >> 4) & 15, j = s & 15;
        int kp = k1 + (r1 << 4) + (BREV4[j] << 8);
#pragma unroll
        for (int par = 0; par < 2; ++par) {
            int k  = 2 * kp + par;
            int km = (N_FFT - k) & (N_FFT - 1);
            float2 A = z[ZADDR(k)];
            float2 B = z[ZADDR(km)];
            float2 Bj = make_float2(B.x, -B.y);
            float2 T0 = make_float2((A.x + Bj.x) * sc, (A.y + Bj.y) * sc);
            float2 dd = csub(A, Bj);
            float2 T1 = make_float2(dd.y * sc, -dd.x * sc);
            Tc[(size_t)d0 * N_FFT + (par << 12) + s] = T0;
            Tc[(size_t)d1 * N_FFT + (par << 12) + s] = T1;
        }
    }
}

template<bool OT>
__global__ __launch_bounds__(256, 4) void conv3_kernel(const float* __restrict__ x,
                                                       const float2* __restrict__ tw,
                                                       const float2* __restrict__ Tc,
                                                       float2* __restrict__ oT,
                                                       float* __restrict__ out) {
    __shared__ float2 z[SEQ];
    const int tid = threadIdx.x;
    const int sb = (blockIdx.x & 7) * 128 + (blockIdx.x >> 3);
    const int d  = sb >> 1;
    const int pb = sb & 1;

    const float* x0 = x + (size_t)(2 * pb) * SEQ * NCH + d;
    const float* x1 = x0 + (size_t)SEQ * NCH;

    float2 xr[16], a[16], ie[16];
#pragma unroll
    for (int n1 = 0; n1 < 16; ++n1) {
        int n = (n1 << 8) + tid;
        xr[n1] = make_float2(x0[(size_t)n * NCH], x1[(size_t)n * NCH]);
    }

#pragma unroll
    for (int par = 0; par < 2; ++par) {
        if (par == 1) __syncthreads();

        if (par == 0) {
#pragma unroll
            for (int n1 = 0; n1 < 16; ++n1) a[n1] = xr[n1];
        } else {
#pragma unroll
            for (int n1 = 0; n1 < 16; ++n1) {
                int n = (n1 << 8) + tid;
                a[n1] = cmul(xr[n1], tw[n]);
            }
        }
        fft16_dif(a);
        {
            float2 w = tw[2 * tid], w2 = cmul(w, w);
            float2 we = make_float2(1.f, 0.f), wo = w;
#pragma unroll
            for (int k1 = 0; k1 < 16; k1 += 2) {
                z[SLOT16(k1, tid)]     = (k1 == 0) ? a[0] : cmul(a[BREV4[k1]], we);
                z[SLOT16(k1 + 1, tid)] = cmul(a[BREV4[k1 + 1]], wo);
                we = cmul(we, w2); wo = cmul(wo, w2);
            }
        }
        __syncthreads();
        {
            const int k1 = tid >> 4, n3 = tid & 15;
#pragma unroll
            for (int n2 = 0; n2 < 16; ++n2)
                a[n2] = z[SLOT16(k1, (n2 << 4) + n3)];
            fft16_dif(a);
            float2 wb = tw[n3 << 5], wb2 = cmul(wb, wb);
            float2 be = make_float2(1.f, 0.f), bo = wb;
#pragma unroll
            for (int r1 = 0; r1 < 16; r1 += 2) {
                z[SLOT16(k1, (r1 << 4) + n3)]       = (r1 == 0) ? a[0] : cmul(a[BREV4[r1]], be);
                z[SLOT16(k1, ((r1 + 1) << 4) + n3)] = cmul(a[BREV4[r1 + 1]], bo);
                be = cmul(be, wb2); bo = cmul(bo, wb2);
            }
        }
        __syncthreads();
        {
            const int k1 = tid >> 4, r1 = tid & 15;
#pragma unroll
            for (int n3 = 0; n3 < 16; ++n3)
                a[n3] = z[SLOT16(k1, (r1 << 4) + n3)];
            fft16_dif(a);
            const float4* tp = (const float4*)(Tc + ((size_t)d << 13) + (par << 12) + (tid << 4));
#pragma unroll
            for (int q = 0; q < 8; ++q) {
                float4 f4 = tp[q];
                a[2 * q]     = cmul(a[2 * q],     make_float2(f4.x, f4.y));
                a[2 * q + 1] = cmul(a[2 * q + 1], make_float2(f4.z, f4.w));
            }
            ifft16_dit(a);
#pragma unroll
            for (int n3 = 0; n3 < 16; ++n3)
                z[SLOT16(k1, (r1 << 4) + n3)] = a[n3];
        }
        __syncthreads();
        {
            const int k1 = tid >> 4, n3 = tid & 15;
            float2 wb = tw[n3 << 5], wb2 = cmul(wb, wb);
            float2 be = make_float2(1.f, 0.f), bo = wb;
#pragma unroll
            for (int r1 = 0; r1 < 16; r1 += 2) {
                float2 v0 = z[SLOT16(k1, (r1 << 4) + n3)];
                float2 v1 = z[SLOT16(k1, ((r1 + 1) << 4) + n3)];
                a[BREV4[r1]]     = (r1 == 0) ? v0 : cmulj(v0, be);
                a[BREV4[r1 + 1]] = cmulj(v1, bo);
                be = cmul(be, wb2); bo = cmul(bo, wb2);
            }
            ifft16_dit(a);
#pragma unroll
            for (int n2 = 0; n2 < 16; ++n2)
                z[SLOT16(k1, (n2 << 4) + n3)] = a[n2];
        }
        __syncthreads();
        {
            float2 w = tw[2 * tid], w2 = cmul(w, w);
            float2 we = make_float2(1.f, 0.f), wo = w;
#pragma unroll
            for (int k1 = 0; k1 < 16; k1 += 2) {
                float2 v0 = z[SLOT16(k1, tid)];
                float2 v1 = z[SLOT16(k1 + 1, tid)];
                a[BREV4[k1]]     = (k1 == 0) ? v0 : cmulj(v0, we);
                a[BREV4[k1 + 1]] = cmulj(v1, wo);
                we = cmul(we, w2); wo = cmul(wo, w2);
            }
            ifft16_dit(a);
        }

        if (par == 0) {
#pragma unroll
            for (int n1 = 0; n1 < 16; ++n1) ie[n1] = a[n1];
        } else {
            if constexpr (OT) {
                float2* op = oT + (((size_t)(pb * NCH + d)) << 12);
#pragma unroll
                for (int n1 = 0; n1 < 16; ++n1) {
                    int n = (n1 << 8) + tid;
                    op[n] = cadd(ie[n1], cmulj(a[n1], tw[n]));
                }
            } else {
                float* o0 = out + (size_t)(2 * pb) * SEQ * NCH + d;
                float* o1 = o0 + (size_t)SEQ * NCH;
#pragma unroll
                for (int n1 = 0; n1 < 16; ++n1) {
                    int n = (n1 << 8) + tid;
                    float2 o = cadd(ie[n1], cmulj(a[n1], tw[n]));
                    o0[(size_t)n * NCH] = o.x;
                    o1[(size_t)n * NCH] = o.y;
                }
            }
        }
    }
}

extern "C" void kernel_launch(void* const* d_in, const int* in_sizes, int n_in,
                              void* d_out, int out_size, void* d_ws, size_t ws_size,
                              hipStream_t stream) {
    (void)in_sizes; (void)n_in; (void)out_size;
    const float* x = (const float*)d_in[0];
    const float* t = (const float*)d_in[1];
    float* out = (float*)d_out;

    float2* tw  = (float2*)d_ws;                   // 8192 f2 = 64 KB
    float2* Tc  = tw + N_FFT;                      // 512*8192 f2 = 33.55 MB
    float2* xoT = Tc + (size_t)NCH * N_FFT;        // 2*512*4096 f2 = 33.55 MB
    float2* tT  = xoT + 2ull * NCH * SEQ;          // 256*8192 f2 = 16.78 MB

    const size_t need_full = sizeof(float2) * ((size_t)N_FFT + (size_t)NCH * N_FFT
                                               + 2ull * NCH * SEQ
                                               + 256ull * N_FFT);   // ~84 MB
    const size_t need_ot   = sizeof(float2) * ((size_t)N_FFT + (size_t)NCH * N_FFT
                                               + 2ull * NCH * SEQ); // ~67.2 MB

    twiddle_init<<<N_FFT / 256, 256, 0, stream>>>(tw);
    if (ws_size >= need_full) {
        transpose_in<<<1536, 256, 0, stream>>>(x, t, xoT, tT);
        tfft3_kernel<<<NCH / 2, 256, 0, stream>>>(tT, tw, Tc);
        conv5_kernel<<<NCH, 512, 0, stream>>>(xoT, tw, Tc);
        transpose_out<<<2048, 256, 0, stream>>>(xoT, out);
    } else if (ws_size >= need_ot) {
        tfft2_kernel<<<NCH / 2, 256, 0, stream>>>(t, tw, Tc);
        conv3_kernel<true><<<1024, 256, 0, stream>>>(x, tw, Tc, xoT, out);
        transpose_out<<<2048, 256, 0, stream>>>(xoT, out);
    } else {
        tfft2_kernel<<<NCH / 2, 256, 0, stream>>>(t, tw, Tc);
        conv3_kernel<false><<<1024, 256, 0, stream>>>(x, tw, Tc, nullptr, out);
    }
}